// Round 3
// baseline (1085.091 us; speedup 1.0000x reference)
//
#include <hip/hip_runtime.h>
#include <cmath>

// CRSDCell bf16-MFMA pipeline, round 3: 2-phase dbuf + global_load_lds weights.
//  - Weights pre-packed chunk-major: P[k0][slot][n][8], k = k0*32 + slot*8 + i.
//    Each K-step's tile is contiguous -> glds width-16 staging.
//  - LDS tiles in k-slot layout [slot][rows][8]: frag reads lane-stride 16B,
//    bank-conflict-free.
//  - Per K-step: issue next glds + act reg-loads, ds_read cur frags,
//    setprio(1) MFMA setprio(0), vmcnt(0), cvt+ds_write next acts, barrier.
// FFT folds exactly: irfft(rfft(h)*s) = s*h. h_prev=r_prev=0 kills Wh/A terms.

typedef __attribute__((ext_vector_type(8)))  short short8;
typedef __attribute__((ext_vector_type(16))) float f32x16;

__device__ __forceinline__ unsigned short f2bf(float f) {
  union { float f; unsigned u; } v; v.f = f;
  unsigned r = v.u + 0x7FFF + ((v.u >> 16) & 1);   // RTNE
  return (unsigned short)(r >> 16);
}
__device__ __forceinline__ float bf2f(unsigned short h) {
  union { unsigned u; float f; } v; v.u = ((unsigned)h) << 16; return v.f;
}
__device__ __forceinline__ f32x16 mfma16(short8 a, short8 b, f32x16 c) {
  return __builtin_amdgcn_mfma_f32_32x32x16_bf16(a, b, c, 0, 0, 0);
}
// copy 1KB: 64 lanes x 16B, contiguous global -> linear LDS (wave-uniform base)
__device__ __forceinline__ void glds1k(const unsigned short* g, short* l, int lane) {
  typedef const __attribute__((address_space(1))) unsigned int* gp_t;
  typedef __attribute__((address_space(3))) unsigned int* lp_t;
  __builtin_amdgcn_global_load_lds((gp_t)(const void*)(g + lane * 8),
                                   (lp_t)(void*)l, 16, 0, 0);
}

// ---------------- weight convert + pack ----------------
// packed offset for (n,k) in [N][K]: (k>>5)*N*32 + ((k>>3)&3)*N*8 + n*8 + (k&7)
__global__ __launch_bounds__(256) void k_wconv(
    const float* __restrict__ wx, const float* __restrict__ key,
    const float* __restrict__ bw, const float* __restrict__ uw,
    const float* __restrict__ fftpw, const float* __restrict__ fg,
    unsigned short* __restrict__ wxp, unsigned short* __restrict__ keyp,
    unsigned short* __restrict__ bwp, unsigned short* __restrict__ uwp,
    unsigned short* __restrict__ fftps) {
  int i = blockIdx.x * 256 + threadIdx.x;
  if (i >= 884736) return;
  float v; int n, k, N; unsigned short* dst;
  if (i < 131072)      { int j = i;          N = 512; k = j & 255; n = j >> 8; v = wx[j];  dst = wxp; }
  else if (i < 229376) { int j = i - 131072; N = 128; k = j % 768; n = j / 768; v = key[j]; dst = keyp; }
  else if (i < 491520) { int j = i - 229376; N = 512; k = j & 511; n = j >> 9; v = bw[j];  dst = bwp; }
  else if (i < 622592) { int j = i - 491520; N = 512; k = j & 255; n = j >> 8; v = uw[j];  dst = uwp; }
  else                 { int j = i - 622592; N = 512; k = j & 511; n = j >> 9; v = fftpw[j] * fg[k]; dst = fftps; }
  dst[(k >> 5) * (N * 32) + ((k >> 3) & 3) * (N * 8) + n * 8 + (k & 7)] = f2bf(v);
}

// ---------------- K1: r_seq (MFMA, BM=128, N=512, K=256) ----------------
__global__ __launch_bounds__(512, 4) void k_rseq(
    const float* __restrict__ x, const unsigned short* __restrict__ wxp,
    const float* __restrict__ wxb, const float* __restrict__ resa,
    const float* __restrict__ rng, const float* __restrict__ rnb,
    float* __restrict__ rout) {
  __shared__ short sA[2][4096];    // [slot4][128][8]
  __shared__ short sW[2][16384];   // [slot4][512][8]
  const int t = threadIdx.x, w = t >> 6, lane = t & 63, lr = lane & 31, lh = lane >> 5;
  const int mw = w >> 2, nw = w & 3;
  const int m0 = blockIdx.x * 128;

  f32x16 acc[2][4];
#pragma unroll
  for (int mi = 0; mi < 2; ++mi)
#pragma unroll
    for (int ni = 0; ni < 4; ++ni)
#pragma unroll
      for (int e = 0; e < 16; ++e) acc[mi][ni][e] = 0.f;

  float4 ar[2];
  auto issue = [&](int sn, int buf) {
#pragma unroll
    for (int u = 0; u < 4; ++u)
      glds1k(wxp + sn * 16384 + (w * 4 + u) * 512, &sW[buf][(w * 4 + u) * 512], lane);
#pragma unroll
    for (int i = 0; i < 2; ++i) {
      int c = t + i * 512, row = c >> 3, kq = c & 7;
      ar[i] = *reinterpret_cast<const float4*>(x + (size_t)(m0 + row) * 256 + sn * 32 + kq * 4);
    }
  };
  auto wr_act = [&](int buf) {
#pragma unroll
    for (int i = 0; i < 2; ++i) {
      int c = t + i * 512, row = c >> 3, kq = c & 7;
      uint2 p;
      p.x = (unsigned)f2bf(ar[i].x) | ((unsigned)f2bf(ar[i].y) << 16);
      p.y = (unsigned)f2bf(ar[i].z) | ((unsigned)f2bf(ar[i].w) << 16);
      *reinterpret_cast<uint2*>(&sA[buf][(kq >> 1) * 1024 + row * 8 + (kq & 1) * 4]) = p;
    }
  };

  issue(0, 0);
  asm volatile("s_waitcnt vmcnt(0)" ::: "memory");
  wr_act(0);
  __syncthreads();

  for (int s = 0; s < 8; ++s) {
    int b = s & 1; bool pf = (s < 7);
    if (pf) issue(s + 1, b ^ 1);
    short8 a[2][2], bb[2][4];
#pragma unroll
    for (int kh = 0; kh < 2; ++kh) {
      int slot = kh * 2 + lh;
#pragma unroll
      for (int mi = 0; mi < 2; ++mi)
        a[kh][mi] = *reinterpret_cast<const short8*>(&sA[b][slot * 1024 + (64 * mw + 32 * mi + lr) * 8]);
#pragma unroll
      for (int ni = 0; ni < 4; ++ni)
        bb[kh][ni] = *reinterpret_cast<const short8*>(&sW[b][slot * 4096 + (128 * nw + 32 * ni + lr) * 8]);
    }
    __builtin_amdgcn_s_setprio(1);
#pragma unroll
    for (int kh = 0; kh < 2; ++kh)
#pragma unroll
      for (int mi = 0; mi < 2; ++mi)
#pragma unroll
        for (int ni = 0; ni < 4; ++ni)
          acc[mi][ni] = mfma16(a[kh][mi], bb[kh][ni], acc[mi][ni]);
    __builtin_amdgcn_s_setprio(0);
    asm volatile("s_waitcnt vmcnt(0)" ::: "memory");
    if (pf) wr_act(b ^ 1);
    __syncthreads();
  }

  // epilogue: z = (1-alpha)*tanh(acc+b), LN
#pragma unroll
  for (int ni = 0; ni < 4; ++ni) {
    int col = 128 * nw + 32 * ni + lr;
    float al = 1.f / (1.f + expf(-resa[col >> 7]));
    float oma = 1.f - al, bbv = wxb[col];
#pragma unroll
    for (int mi = 0; mi < 2; ++mi)
#pragma unroll
      for (int r = 0; r < 16; ++r)
        acc[mi][ni][r] = oma * tanhf(acc[mi][ni][r] + bbv);
  }
  float* red = reinterpret_cast<float*>(sW);   // red1 @0[512], red2 @512, stats @1024
#pragma unroll
  for (int mi = 0; mi < 2; ++mi) {
    int mrow = mw * 2 + mi;
#pragma unroll
    for (int r = 0; r < 16; ++r) {
      float s1 = acc[mi][0][r] + acc[mi][1][r] + acc[mi][2][r] + acc[mi][3][r];
      float s2 = acc[mi][0][r] * acc[mi][0][r] + acc[mi][1][r] * acc[mi][1][r] +
                 acc[mi][2][r] * acc[mi][2][r] + acc[mi][3][r] * acc[mi][3][r];
#pragma unroll
      for (int m = 1; m <= 16; m <<= 1) { s1 += __shfl_xor(s1, m); s2 += __shfl_xor(s2, m); }
      int rl = (r & 3) + 8 * (r >> 2) + 4 * lh;
      if (lr == r) { red[(nw * 4 + mrow) * 32 + rl] = s1; red[512 + (nw * 4 + mrow) * 32 + rl] = s2; }
    }
  }
  __syncthreads();
  if (t < 128) {
    int mrow = t >> 5, rl = t & 31;
    float s1 = 0.f, s2 = 0.f;
#pragma unroll
    for (int n = 0; n < 4; ++n) { s1 += red[(n * 4 + mrow) * 32 + rl]; s2 += red[512 + (n * 4 + mrow) * 32 + rl]; }
    float mean = s1 * (1.f / 512.f);
    float var = s2 * (1.f / 512.f) - mean * mean;
    float rstd = rsqrtf(var + 1e-5f);
    red[1024 + (mrow * 32 + rl) * 2] = mean;
    red[1024 + (mrow * 32 + rl) * 2 + 1] = rstd;
  }
  __syncthreads();
#pragma unroll
  for (int mi = 0; mi < 2; ++mi) {
    int mrow = mw * 2 + mi;
#pragma unroll
    for (int q = 0; q < 4; ++q) {
      float4 stA = *reinterpret_cast<float4*>(&red[1024 + (mrow * 32 + 8 * q + 4 * lh) * 2]);
      float4 stB = *reinterpret_cast<float4*>(&red[1024 + (mrow * 32 + 8 * q + 4 * lh) * 2 + 4]);
      float mean[4] = {stA.x, stA.z, stB.x, stB.z};
      float rstd[4] = {stA.y, stA.w, stB.y, stB.w};
#pragma unroll
      for (int ni = 0; ni < 4; ++ni) {
        int col = 128 * nw + 32 * ni + lr;
        float g = rng[col], bbv = rnb[col];
#pragma unroll
        for (int e = 0; e < 4; ++e) {
          int r = 4 * q + e;
          int grow = m0 + 64 * mw + 32 * mi + 8 * q + 4 * lh + e;
          rout[(size_t)grow * 512 + col] = (acc[mi][ni][r] - mean[e]) * rstd[e] * g + bbv;
        }
      }
    }
  }
}

// ---------------- K2: k + q partials (MFMA, BM=256, N=128, K=768) ----------------
__global__ __launch_bounds__(512, 4) void k_kq(
    const float* __restrict__ rseq, const float* __restrict__ x,
    const unsigned short* __restrict__ keyp, const float* __restrict__ keyb,
    float* __restrict__ partial) {
  __shared__ short sA[2][8192];    // [slot4][256][8]
  __shared__ short sW[2][4096];    // [slot4][128][8]
  const int t = threadIdx.x, w = t >> 6, lane = t & 63, lr = lane & 31, lh = lane >> 5;
  const int mw = w >> 1, nw = w & 1;
  const int m0 = blockIdx.x * 256;

  f32x16 acc[2][2];
#pragma unroll
  for (int mi = 0; mi < 2; ++mi)
#pragma unroll
    for (int ni = 0; ni < 2; ++ni)
#pragma unroll
      for (int e = 0; e < 16; ++e) acc[mi][ni][e] = 0.f;

  float4 ar[4];
  auto issue = [&](int sn, int buf) {
    glds1k(keyp + sn * 4096 + w * 512, &sW[buf][w * 512], lane);
    const float* src; int str, kb;
    if (sn < 16) { src = rseq; str = 512; kb = sn * 32; }
    else         { src = x;    str = 256; kb = (sn - 16) * 32; }
#pragma unroll
    for (int i = 0; i < 4; ++i) {
      int c = t + i * 512, row = c >> 3, kq = c & 7;
      ar[i] = *reinterpret_cast<const float4*>(src + (size_t)(m0 + row) * str + kb + kq * 4);
    }
  };
  auto wr_act = [&](int buf) {
#pragma unroll
    for (int i = 0; i < 4; ++i) {
      int c = t + i * 512, row = c >> 3, kq = c & 7;
      uint2 p;
      p.x = (unsigned)f2bf(ar[i].x) | ((unsigned)f2bf(ar[i].y) << 16);
      p.y = (unsigned)f2bf(ar[i].z) | ((unsigned)f2bf(ar[i].w) << 16);
      *reinterpret_cast<uint2*>(&sA[buf][(kq >> 1) * 2048 + row * 8 + (kq & 1) * 4]) = p;
    }
  };

  issue(0, 0);
  asm volatile("s_waitcnt vmcnt(0)" ::: "memory");
  wr_act(0);
  __syncthreads();

  for (int s = 0; s < 24; ++s) {
    int b = s & 1; bool pf = (s < 23);
    if (pf) issue(s + 1, b ^ 1);
    short8 a[2][2], bb[2][2];
#pragma unroll
    for (int kh = 0; kh < 2; ++kh) {
      int slot = kh * 2 + lh;
#pragma unroll
      for (int mi = 0; mi < 2; ++mi)
        a[kh][mi] = *reinterpret_cast<const short8*>(&sA[b][slot * 2048 + (64 * mw + 32 * mi + lr) * 8]);
#pragma unroll
      for (int ni = 0; ni < 2; ++ni)
        bb[kh][ni] = *reinterpret_cast<const short8*>(&sW[b][slot * 1024 + (64 * nw + 32 * ni + lr) * 8]);
    }
    __builtin_amdgcn_s_setprio(1);
#pragma unroll
    for (int kh = 0; kh < 2; ++kh)
#pragma unroll
      for (int mi = 0; mi < 2; ++mi)
#pragma unroll
        for (int ni = 0; ni < 2; ++ni)
          acc[mi][ni] = mfma16(a[kh][mi], bb[kh][ni], acc[mi][ni]);
    __builtin_amdgcn_s_setprio(0);
    asm volatile("s_waitcnt vmcnt(0)" ::: "memory");
    if (pf) wr_act(b ^ 1);
    __syncthreads();
  }

  // + bias; per-row l2 scale; column partials of l2norm(k)
#pragma unroll
  for (int ni = 0; ni < 2; ++ni) {
    int col = 64 * nw + 32 * ni + lr;
    float bbv = keyb[col];
#pragma unroll
    for (int mi = 0; mi < 2; ++mi)
#pragma unroll
      for (int r = 0; r < 16; ++r) acc[mi][ni][r] += bbv;
  }
  float* red = reinterpret_cast<float*>(sA);   // s2 @0[512], scale @512[256], qp @768[512]
#pragma unroll
  for (int mi = 0; mi < 2; ++mi) {
    int mrow = mw * 2 + mi;
#pragma unroll
    for (int r = 0; r < 16; ++r) {
      float s2 = acc[mi][0][r] * acc[mi][0][r] + acc[mi][1][r] * acc[mi][1][r];
#pragma unroll
      for (int m = 1; m <= 16; m <<= 1) s2 += __shfl_xor(s2, m);
      int rl = (r & 3) + 8 * (r >> 2) + 4 * lh;
      if (lr == r) red[(nw * 8 + mrow) * 32 + rl] = s2;
    }
  }
  __syncthreads();
  if (t < 256) {
    int mrow = t >> 5, rl = t & 31;
    float s = red[(0 * 8 + mrow) * 32 + rl] + red[(8 + mrow) * 32 + rl];
    red[512 + mrow * 32 + rl] = 1.f / fmaxf(sqrtf(s), 1e-8f);
  }
  __syncthreads();
  float p0 = 0.f, p1 = 0.f;
#pragma unroll
  for (int mi = 0; mi < 2; ++mi) {
    int mrow = mw * 2 + mi;
#pragma unroll
    for (int q = 0; q < 4; ++q) {
      float4 sc4 = *reinterpret_cast<float4*>(&red[512 + mrow * 32 + 8 * q + 4 * lh]);
      float sc[4] = {sc4.x, sc4.y, sc4.z, sc4.w};
#pragma unroll
      for (int e = 0; e < 4; ++e) {
        int r = 4 * q + e;
        p0 += acc[mi][0][r] * sc[e];
        p1 += acc[mi][1][r] * sc[e];
      }
    }
  }
  p0 += __shfl_xor(p0, 32);
  p1 += __shfl_xor(p1, 32);
  if (lh == 0) {
    red[768 + mw * 128 + 64 * nw + lr]      = p0;
    red[768 + mw * 128 + 64 * nw + 32 + lr] = p1;
  }
  __syncthreads();
  if (t < 128)
    partial[(size_t)blockIdx.x * 128 + t] =
        red[768 + t] + red[768 + 128 + t] + red[768 + 256 + t] + red[768 + 384 + t];
}

// ---------------- q reduce ----------------
__global__ __launch_bounds__(256) void k_qred(const float* __restrict__ partial,
                                              float* __restrict__ q_ws) {
  int gid = blockIdx.x * 256 + threadIdx.x;   // 0..1023
  int b = gid >> 7, c = gid & 127;
  float s = 0.f;
  for (int i = 0; i < 32; ++i) s += partial[(size_t)(b * 32 + i) * 128 + c];
  q_ws[gid] = s * (1.f / 8192.f);
}

// ---------------- cvec = fftn_b @ fftp_w^T (raw fftp) ----------------
__global__ __launch_bounds__(256) void k_cvec(const float* __restrict__ fb,
                                              const float* __restrict__ fftpw,
                                              float* __restrict__ cvec) {
  int o = blockIdx.x * 256 + threadIdx.x;     // 0..511
  const float* w = fftpw + (size_t)o * 512;
  float s = 0.f;
  for (int k = 0; k < 512; ++k) s += fb[k] * w[k];
  cvec[o] = s;
}

// ---------------- memory (episodic + hebbian) ----------------
__global__ __launch_bounds__(256) void k_mem(
    const float* __restrict__ q_ws, const float* __restrict__ mkeys,
    const float* __restrict__ mvals, const float* __restrict__ hebH,
    const float* __restrict__ rmw, const float* __restrict__ rmb,
    const float* __restrict__ mixl, float* __restrict__ hm) {
  const int b = blockIdx.x, t = threadIdx.x;
  __shared__ float qv[128];
  __shared__ float ssim[256];
  __shared__ float red[256];
  __shared__ float tval[8];
  __shared__ int tidx[8];
  __shared__ float wsm[8];
  __shared__ float vcs[128];

  if (t < 128) qv[t] = q_ws[b * 128 + t];
  __syncthreads();
  red[t] = (t < 128) ? qv[t] * qv[t] : 0.f;
  __syncthreads();
  for (int s = 128; s > 0; s >>= 1) {
    if (t < s) red[t] += red[t + s];
    __syncthreads();
  }
  float qsc = 1.f / fmaxf(sqrtf(red[0]), 1e-8f);
  {
    const float* mk = mkeys + ((size_t)b * 256 + t) * 128;
    float dot = 0.f, ms = 0.f;
    for (int k = 0; k < 128; ++k) { float mv = mk[k]; dot += qv[k] * mv; ms += mv * mv; }
    ssim[t] = dot * qsc / fmaxf(sqrtf(ms), 1e-8f);
  }
  __syncthreads();
  for (int it = 0; it < 8; ++it) {
    if (t < 64) {
      float bv = -1e30f; int bi = 0;
#pragma unroll
      for (int u = 0; u < 4; ++u) {
        int m = t * 4 + u;
        float v = ssim[m];
        if (v > bv) { bv = v; bi = m; }
      }
      for (int off = 32; off; off >>= 1) {
        float ov = __shfl_xor(bv, off, 64);
        int oi = __shfl_xor(bi, off, 64);
        if (ov > bv || (ov == bv && oi < bi)) { bv = ov; bi = oi; }
      }
      if (t == 0) { tval[it] = bv; tidx[it] = bi; ssim[bi] = -1e30f; }
    }
    __syncthreads();
  }
  if (t == 0) {
    float m0 = tval[0], sum = 0.f, e[8];
#pragma unroll
    for (int i = 0; i < 8; ++i) { e[i] = expf(tval[i] - m0); sum += e[i]; }
#pragma unroll
    for (int i = 0; i < 8; ++i) wsm[i] = e[i] / sum;
  }
  __syncthreads();
  float mix = 1.f / (1.f + expf(-mixl[0]));
  if (t < 128) {
    float vh = 0.f;
#pragma unroll
    for (int i = 0; i < 8; ++i) vh += wsm[i] * mvals[((size_t)b * 256 + tidx[i]) * 128 + t];
    float vhb = 0.f;
    const float* H = hebH + (size_t)b * 128 * 128;
    for (int k = 0; k < 128; ++k) vhb += qv[k] * H[k * 128 + t];
    vcs[t] = mix * vh + (1.f - mix) * vhb;
  }
  __syncthreads();
  for (int h = t; h < 512; h += 256) {
    float sum = rmb[h];
    const float* wr = rmw + (size_t)h * 128;
    for (int v = 0; v < 128; ++v) sum += vcs[v] * wr[v];
    hm[b * 512 + h] = sum;
  }
}

// ---------------- fused h_tilde -> LN -> fftp GEMM -> hs (BM=64) ----------------
__global__ __launch_bounds__(512, 2) void k_fused(
    const float* __restrict__ rseq, const float* __restrict__ x,
    const unsigned short* __restrict__ bwp, const unsigned short* __restrict__ uwp,
    const float* __restrict__ ub, const unsigned short* __restrict__ fftps,
    const float* __restrict__ fftpb, const float* __restrict__ fmix,
    const float* __restrict__ cvec, const float* __restrict__ hm,
    float* __restrict__ hs) {
  __shared__ short sH[64 * 512];   // [slot64][64][8]
  __shared__ short sW[2][16384];   // [slot4][512][8]
  __shared__ short sA[2][2048];    // [slot4][64][8]
  const int t = threadIdx.x, w = t >> 6, lane = t & 63, lr = lane & 31, lh = lane >> 5;
  const int mw = w >> 2, nw = w & 3;
  const int m0 = blockIdx.x * 64;
  const int bidx = m0 >> 13;

  f32x16 acc[4];
#pragma unroll
  for (int ni = 0; ni < 4; ++ni)
#pragma unroll
    for (int e = 0; e < 16; ++e) acc[ni][e] = 0.f;

  float4 ar;
  auto issue1 = [&](int sn, int buf) {
    const unsigned short* wsrc = (sn < 16) ? (bwp + sn * 16384) : (uwp + (sn - 16) * 16384);
#pragma unroll
    for (int u = 0; u < 4; ++u)
      glds1k(wsrc + (w * 4 + u) * 512, &sW[buf][(w * 4 + u) * 512], lane);
    const float* src; int str, kb;
    if (sn < 16) { src = rseq; str = 512; kb = sn * 32; }
    else         { src = x;    str = 256; kb = (sn - 16) * 32; }
    int row = t >> 3, kq = t & 7;
    ar = *reinterpret_cast<const float4*>(src + (size_t)(m0 + row) * str + kb + kq * 4);
  };
  auto wr_act = [&](int buf) {
    int row = t >> 3, kq = t & 7;
    uint2 p;
    p.x = (unsigned)f2bf(ar.x) | ((unsigned)f2bf(ar.y) << 16);
    p.y = (unsigned)f2bf(ar.z) | ((unsigned)f2bf(ar.w) << 16);
    *reinterpret_cast<uint2*>(&sA[buf][(kq >> 1) * 512 + row * 8 + (kq & 1) * 4]) = p;
  };

  // ---- GEMM1: h_pre = [r,x] @ [Bw,Uw]^T ----
  issue1(0, 0);
  asm volatile("s_waitcnt vmcnt(0)" ::: "memory");
  wr_act(0);
  __syncthreads();
  for (int s = 0; s < 24; ++s) {
    int b = s & 1; bool pf = (s < 23);
    if (pf) issue1(s + 1, b ^ 1);
    short8 a[2], bb[2][4];
#pragma unroll
    for (int kh = 0; kh < 2; ++kh) {
      int slot = kh * 2 + lh;
      a[kh] = *reinterpret_cast<const short8*>(&sA[b][slot * 512 + (32 * mw + lr) * 8]);
#pragma unroll
      for (int ni = 0; ni < 4; ++ni)
        bb[kh][ni] = *reinterpret_cast<const short8*>(&sW[b][slot * 4096 + (128 * nw + 32 * ni + lr) * 8]);
    }
    __builtin_amdgcn_s_setprio(1);
#pragma unroll
    for (int kh = 0; kh < 2; ++kh)
#pragma unroll
      for (int ni = 0; ni < 4; ++ni)
        acc[ni] = mfma16(a[kh], bb[kh][ni], acc[ni]);
    __builtin_amdgcn_s_setprio(0);
    asm volatile("s_waitcnt vmcnt(0)" ::: "memory");
    if (pf) wr_act(b ^ 1);
    __syncthreads();
  }

  // ---- epilogue1: gelu, LN stats, pack h~, write sH (k-slot layout) ----
#pragma unroll
  for (int ni = 0; ni < 4; ++ni) {
    int col = 128 * nw + 32 * ni + lr;
    float ubc = ub[col];
#pragma unroll
    for (int r = 0; r < 16; ++r) {
      float pre = acc[ni][r] + ubc;
      acc[ni][r] = 0.5f * pre * (1.f + erff(pre * 0.70710678118654752f));
    }
  }
  float* red = reinterpret_cast<float*>(sW);  // red1 @0[256], red2 @256, stats @512[128]
#pragma unroll
  for (int r = 0; r < 16; ++r) {
    float s1 = acc[0][r] + acc[1][r] + acc[2][r] + acc[3][r];
    float s2 = acc[0][r] * acc[0][r] + acc[1][r] * acc[1][r] +
               acc[2][r] * acc[2][r] + acc[3][r] * acc[3][r];
#pragma unroll
    for (int m = 1; m <= 16; m <<= 1) { s1 += __shfl_xor(s1, m); s2 += __shfl_xor(s2, m); }
    int rl = (r & 3) + 8 * (r >> 2) + 4 * lh;
    if (lr == r) { red[(nw * 2 + mw) * 32 + rl] = s1; red[256 + (nw * 2 + mw) * 32 + rl] = s2; }
  }
  __syncthreads();
  if (w == 0) {
    int mw_ = lane >> 5, rl = lane & 31;
    float s1 = 0.f, s2 = 0.f;
#pragma unroll
    for (int n = 0; n < 4; ++n) { s1 += red[(n * 2 + mw_) * 32 + rl]; s2 += red[256 + (n * 2 + mw_) * 32 + rl]; }
    float mean = s1 * (1.f / 512.f);
    float var = s2 * (1.f / 512.f) - mean * mean;
    float rstd = rsqrtf(var + 1e-5f);
    red[512 + (mw_ * 32 + rl) * 2] = mean;
    red[512 + (mw_ * 32 + rl) * 2 + 1] = rstd;
  }
  __syncthreads();
  unsigned htp[4][8];
#pragma unroll
  for (int ni = 0; ni < 4; ++ni)
#pragma unroll
    for (int p = 0; p < 8; ++p)
      htp[ni][p] = (unsigned)f2bf(acc[ni][2 * p]) | ((unsigned)f2bf(acc[ni][2 * p + 1]) << 16);
#pragma unroll
  for (int q = 0; q < 4; ++q) {
    float4 stA = *reinterpret_cast<float4*>(&red[512 + (mw * 32 + 8 * q + 4 * lh) * 2]);
    float4 stB = *reinterpret_cast<float4*>(&red[512 + (mw * 32 + 8 * q + 4 * lh) * 2 + 4]);
    float mean[4] = {stA.x, stA.z, stB.x, stB.z};
    float rstd[4] = {stA.y, stA.w, stB.y, stB.w};
#pragma unroll
    for (int ni = 0; ni < 4; ++ni) {
      int col = 128 * nw + 32 * ni + lr;
#pragma unroll
      for (int e = 0; e < 4; ++e) {
        int r = 4 * q + e;
        float z = (acc[ni][r] - mean[e]) * rstd[e];
        int rloc = 32 * mw + 8 * q + 4 * lh + e;
        sH[(col >> 3) * 512 + rloc * 8 + (col & 7)] = (short)f2bf(z);
      }
    }
  }
#pragma unroll
  for (int ni = 0; ni < 4; ++ni)
#pragma unroll
    for (int e = 0; e < 16; ++e) acc[ni][e] = 0.f;
  __syncthreads();

  // ---- GEMM2: h_norm @ (fftp*g)^T ----
#pragma unroll
  for (int u = 0; u < 4; ++u)
    glds1k(fftps + (w * 4 + u) * 512, &sW[0][(w * 4 + u) * 512], lane);
  asm volatile("s_waitcnt vmcnt(0)" ::: "memory");
  __syncthreads();
  for (int s = 0; s < 16; ++s) {
    int b = s & 1; bool pf = (s < 15);
    if (pf) {
#pragma unroll
      for (int u = 0; u < 4; ++u)
        glds1k(fftps + (s + 1) * 16384 + (w * 4 + u) * 512, &sW[b ^ 1][(w * 4 + u) * 512], lane);
    }
    short8 a[2], bb[2][4];
#pragma unroll
    for (int kh = 0; kh < 2; ++kh) {
      int slot = kh * 2 + lh;
      a[kh] = *reinterpret_cast<const short8*>(&sH[(s * 4 + slot) * 512 + (32 * mw + lr) * 8]);
#pragma unroll
      for (int ni = 0; ni < 4; ++ni)
        bb[kh][ni] = *reinterpret_cast<const short8*>(&sW[b][slot * 4096 + (128 * nw + 32 * ni + lr) * 8]);
    }
    __builtin_amdgcn_s_setprio(1);
#pragma unroll
    for (int kh = 0; kh < 2; ++kh)
#pragma unroll
      for (int ni = 0; ni < 4; ++ni)
        acc[ni] = mfma16(a[kh], bb[kh][ni], acc[ni]);
    __builtin_amdgcn_s_setprio(0);
    asm volatile("s_waitcnt vmcnt(0)" ::: "memory");
    __syncthreads();
  }

  // ---- epilogue2: combine ----
  const float s = 1.f / (1.f + expf(-fmix[0]));
  const float s2f = s * s, oms = 1.f - s;
#pragma unroll
  for (int ni = 0; ni < 4; ++ni) {
    int col = 128 * nw + 32 * ni + lr;
    float base = s2f * cvec[col] + s * fftpb[col] + 0.5f * hm[bidx * 512 + col];
#pragma unroll
    for (int p = 0; p < 8; ++p) {
      unsigned pk = htp[ni][p];
      int r0 = 2 * p;
      int rloc = 32 * mw + (r0 & 3) + 8 * (r0 >> 2) + 4 * lh;
      float o0 = oms * bf2f((unsigned short)(pk & 0xFFFF)) + s2f * acc[ni][r0] + base;
      float o1 = oms * bf2f((unsigned short)(pk >> 16)) + s2f * acc[ni][r0 + 1] + base;
      hs[(size_t)(m0 + rloc) * 512 + col] = o0;
      hs[(size_t)(m0 + rloc + 1) * 512 + col] = o1;
    }
  }
}

extern "C" void kernel_launch(void* const* d_in, const int* in_sizes, int n_in,
                              void* d_out, int out_size, void* d_ws, size_t ws_size,
                              hipStream_t stream) {
  (void)in_sizes; (void)n_in; (void)out_size; (void)ws_size;
  const float* x     = (const float*)d_in[0];
  const float* Wxw   = (const float*)d_in[1];
  const float* Wxb   = (const float*)d_in[2];
  const float* resa  = (const float*)d_in[4];
  const float* Bw    = (const float*)d_in[6];
  const float* Uw    = (const float*)d_in[7];
  const float* Ub    = (const float*)d_in[8];
  const float* fg    = (const float*)d_in[9];
  const float* fb    = (const float*)d_in[10];
  const float* fftpw = (const float*)d_in[11];
  const float* fftpb = (const float*)d_in[12];
  const float* fmix  = (const float*)d_in[13];
  const float* mixl  = (const float*)d_in[14];
  const float* keyw  = (const float*)d_in[15];
  const float* keyb  = (const float*)d_in[16];
  const float* rmw   = (const float*)d_in[19];
  const float* rmb   = (const float*)d_in[20];
  const float* rng   = (const float*)d_in[21];
  const float* rnb   = (const float*)d_in[22];
  const float* mkeys = (const float*)d_in[23];
  const float* mvals = (const float*)d_in[24];
  const float* hebH  = (const float*)d_in[25];

  float* outp = (float*)d_out;
  float* hs   = outp;                               // (B,T,512)
  float* rout = outp + (size_t)65536 * 512;         // (B,T,512)

  unsigned short* wsu = (unsigned short*)d_ws;
  unsigned short* wxp    = wsu;                     // 131072
  unsigned short* keyp   = wsu + 131072;            // 98304
  unsigned short* bwp    = wsu + 229376;            // 262144
  unsigned short* uwp    = wsu + 491520;            // 131072
  unsigned short* fftps  = wsu + 622592;            // 262144
  float* wsf     = (float*)d_ws;
  float* partial = wsf + 524288;                    // 256*128
  float* q_ws    = wsf + 589824;                    // 1024
  float* hm      = wsf + 590848;                    // 4096
  float* cvec    = wsf + 594944;                    // 512

  k_wconv<<<3456, 256, 0, stream>>>(Wxw, keyw, Bw, Uw, fftpw, fg,
                                    wxp, keyp, bwp, uwp, fftps);
  k_cvec <<<2,    256, 0, stream>>>(fb, fftpw, cvec);
  k_rseq <<<512,  512, 0, stream>>>(x, wxp, Wxb, resa, rng, rnb, rout);
  k_kq   <<<256,  512, 0, stream>>>(rout, x, keyp, keyb, partial);
  k_qred <<<4,    256, 0, stream>>>(partial, q_ws);
  k_mem  <<<8,    256, 0, stream>>>(q_ws, mkeys, mvals, hebH, rmw, rmb, mixl, hm);
  k_fused<<<1024, 512, 0, stream>>>(rout, x, bwp, uwp, Ub, fftps, fftpb,
                                    fmix, cvec, hm, hs);
}

// Round 4
// 464.818 us; speedup vs baseline: 2.3344x; 2.3344x over previous
//
#include <hip/hip_runtime.h>
#include <cmath>

// CRSDCell bf16-MFMA pipeline, round 4: fix VGPR spill (launch_bounds caps).
//  - Weights pre-packed chunk-major: P[k0][slot][n][8], k = k0*32 + slot*8 + i.
//    Each K-step's tile is contiguous -> glds width-16 staging.
//  - LDS tiles in k-slot layout [slot][rows][8]: frag reads lane-stride 16B,
//    bank-conflict-free.
//  - Per K-step: issue next glds + act reg-loads, ds_read cur frags,
//    setprio(1) MFMA setprio(0), vmcnt(0), cvt+ds_write next acts, barrier.
//  - k_rseq: BM=64 (acc 64 f/thread), launch_bounds(512,2) -> no spill.
// FFT folds exactly: irfft(rfft(h)*s) = s*h. h_prev=r_prev=0 kills Wh/A terms.

typedef __attribute__((ext_vector_type(8)))  short short8;
typedef __attribute__((ext_vector_type(16))) float f32x16;

__device__ __forceinline__ unsigned short f2bf(float f) {
  union { float f; unsigned u; } v; v.f = f;
  unsigned r = v.u + 0x7FFF + ((v.u >> 16) & 1);   // RTNE
  return (unsigned short)(r >> 16);
}
__device__ __forceinline__ float bf2f(unsigned short h) {
  union { unsigned u; float f; } v; v.u = ((unsigned)h) << 16; return v.f;
}
__device__ __forceinline__ f32x16 mfma16(short8 a, short8 b, f32x16 c) {
  return __builtin_amdgcn_mfma_f32_32x32x16_bf16(a, b, c, 0, 0, 0);
}
// copy 1KB: 64 lanes x 16B, contiguous global -> linear LDS (wave-uniform base)
__device__ __forceinline__ void glds1k(const unsigned short* g, short* l, int lane) {
  typedef const __attribute__((address_space(1))) unsigned int* gp_t;
  typedef __attribute__((address_space(3))) unsigned int* lp_t;
  __builtin_amdgcn_global_load_lds((gp_t)(const void*)(g + lane * 8),
                                   (lp_t)(void*)l, 16, 0, 0);
}

// ---------------- weight convert + pack ----------------
// packed offset for (n,k) in [N][K]: (k>>5)*N*32 + ((k>>3)&3)*N*8 + n*8 + (k&7)
__global__ __launch_bounds__(256) void k_wconv(
    const float* __restrict__ wx, const float* __restrict__ key,
    const float* __restrict__ bw, const float* __restrict__ uw,
    const float* __restrict__ fftpw, const float* __restrict__ fg,
    unsigned short* __restrict__ wxp, unsigned short* __restrict__ keyp,
    unsigned short* __restrict__ bwp, unsigned short* __restrict__ uwp,
    unsigned short* __restrict__ fftps) {
  int i = blockIdx.x * 256 + threadIdx.x;
  if (i >= 884736) return;
  float v; int n, k, N; unsigned short* dst;
  if (i < 131072)      { int j = i;          N = 512; k = j & 255; n = j >> 8; v = wx[j];  dst = wxp; }
  else if (i < 229376) { int j = i - 131072; N = 128; k = j % 768; n = j / 768; v = key[j]; dst = keyp; }
  else if (i < 491520) { int j = i - 229376; N = 512; k = j & 511; n = j >> 9; v = bw[j];  dst = bwp; }
  else if (i < 622592) { int j = i - 491520; N = 512; k = j & 255; n = j >> 8; v = uw[j];  dst = uwp; }
  else                 { int j = i - 622592; N = 512; k = j & 511; n = j >> 9; v = fftpw[j] * fg[k]; dst = fftps; }
  dst[(k >> 5) * (N * 32) + ((k >> 3) & 3) * (N * 8) + n * 8 + (k & 7)] = f2bf(v);
}

// ---------------- K1: r_seq (MFMA, BM=64, N=512, K=256) ----------------
__global__ __launch_bounds__(512, 2) void k_rseq(
    const float* __restrict__ x, const unsigned short* __restrict__ wxp,
    const float* __restrict__ wxb, const float* __restrict__ resa,
    const float* __restrict__ rng, const float* __restrict__ rnb,
    float* __restrict__ rout) {
  __shared__ short sA[2][2048];    // [slot4][64][8]
  __shared__ short sW[2][16384];   // [slot4][512][8]
  const int t = threadIdx.x, w = t >> 6, lane = t & 63, lr = lane & 31, lh = lane >> 5;
  const int mw = w >> 2, nw = w & 3;
  const int m0 = blockIdx.x * 64;

  f32x16 acc[4];
#pragma unroll
  for (int ni = 0; ni < 4; ++ni)
#pragma unroll
    for (int e = 0; e < 16; ++e) acc[ni][e] = 0.f;

  float4 ar;
  auto issue = [&](int sn, int buf) {
#pragma unroll
    for (int u = 0; u < 4; ++u)
      glds1k(wxp + sn * 16384 + (w * 4 + u) * 512, &sW[buf][(w * 4 + u) * 512], lane);
    int row = t >> 3, kq = t & 7;
    ar = *reinterpret_cast<const float4*>(x + (size_t)(m0 + row) * 256 + sn * 32 + kq * 4);
  };
  auto wr_act = [&](int buf) {
    int row = t >> 3, kq = t & 7;
    uint2 p;
    p.x = (unsigned)f2bf(ar.x) | ((unsigned)f2bf(ar.y) << 16);
    p.y = (unsigned)f2bf(ar.z) | ((unsigned)f2bf(ar.w) << 16);
    *reinterpret_cast<uint2*>(&sA[buf][(kq >> 1) * 512 + row * 8 + (kq & 1) * 4]) = p;
  };

  issue(0, 0);
  asm volatile("s_waitcnt vmcnt(0)" ::: "memory");
  wr_act(0);
  __syncthreads();

  for (int s = 0; s < 8; ++s) {
    int b = s & 1; bool pf = (s < 7);
    if (pf) issue(s + 1, b ^ 1);
    short8 a[2], bb[2][4];
#pragma unroll
    for (int kh = 0; kh < 2; ++kh) {
      int slot = kh * 2 + lh;
      a[kh] = *reinterpret_cast<const short8*>(&sA[b][slot * 512 + (32 * mw + lr) * 8]);
#pragma unroll
      for (int ni = 0; ni < 4; ++ni)
        bb[kh][ni] = *reinterpret_cast<const short8*>(&sW[b][slot * 4096 + (128 * nw + 32 * ni + lr) * 8]);
    }
    __builtin_amdgcn_s_setprio(1);
#pragma unroll
    for (int kh = 0; kh < 2; ++kh)
#pragma unroll
      for (int ni = 0; ni < 4; ++ni)
        acc[ni] = mfma16(a[kh], bb[kh][ni], acc[ni]);
    __builtin_amdgcn_s_setprio(0);
    asm volatile("s_waitcnt vmcnt(0)" ::: "memory");
    if (pf) wr_act(b ^ 1);
    __syncthreads();
  }

  // epilogue: z = (1-alpha)*tanh(acc+b), LN over 512 cols
#pragma unroll
  for (int ni = 0; ni < 4; ++ni) {
    int col = 128 * nw + 32 * ni + lr;
    float al = 1.f / (1.f + expf(-resa[col >> 7]));
    float oma = 1.f - al, bbv = wxb[col];
#pragma unroll
    for (int r = 0; r < 16; ++r)
      acc[ni][r] = oma * tanhf(acc[ni][r] + bbv);
  }
  float* red = reinterpret_cast<float*>(sW);  // red1 @0[256], red2 @256, stats @512[128*2]
#pragma unroll
  for (int r = 0; r < 16; ++r) {
    float s1 = acc[0][r] + acc[1][r] + acc[2][r] + acc[3][r];
    float s2 = acc[0][r] * acc[0][r] + acc[1][r] * acc[1][r] +
               acc[2][r] * acc[2][r] + acc[3][r] * acc[3][r];
#pragma unroll
    for (int m = 1; m <= 16; m <<= 1) { s1 += __shfl_xor(s1, m); s2 += __shfl_xor(s2, m); }
    int rl = (r & 3) + 8 * (r >> 2) + 4 * lh;
    if (lr == r) { red[(nw * 2 + mw) * 32 + rl] = s1; red[256 + (nw * 2 + mw) * 32 + rl] = s2; }
  }
  __syncthreads();
  if (w == 0) {
    int mw_ = lane >> 5, rl = lane & 31;
    float s1 = 0.f, s2 = 0.f;
#pragma unroll
    for (int n = 0; n < 4; ++n) { s1 += red[(n * 2 + mw_) * 32 + rl]; s2 += red[256 + (n * 2 + mw_) * 32 + rl]; }
    float mean = s1 * (1.f / 512.f);
    float var = s2 * (1.f / 512.f) - mean * mean;
    float rstd = rsqrtf(var + 1e-5f);
    red[512 + (mw_ * 32 + rl) * 2] = mean;
    red[512 + (mw_ * 32 + rl) * 2 + 1] = rstd;
  }
  __syncthreads();
#pragma unroll
  for (int q = 0; q < 4; ++q) {
    float4 stA = *reinterpret_cast<float4*>(&red[512 + (mw * 32 + 8 * q + 4 * lh) * 2]);
    float4 stB = *reinterpret_cast<float4*>(&red[512 + (mw * 32 + 8 * q + 4 * lh) * 2 + 4]);
    float mean[4] = {stA.x, stA.z, stB.x, stB.z};
    float rstd[4] = {stA.y, stA.w, stB.y, stB.w};
#pragma unroll
    for (int ni = 0; ni < 4; ++ni) {
      int col = 128 * nw + 32 * ni + lr;
      float g = rng[col], bbv = rnb[col];
#pragma unroll
      for (int e = 0; e < 4; ++e) {
        int r = 4 * q + e;
        int grow = m0 + 32 * mw + 8 * q + 4 * lh + e;
        rout[(size_t)grow * 512 + col] = (acc[ni][r] - mean[e]) * rstd[e] * g + bbv;
      }
    }
  }
}

// ---------------- K2: k + q partials (MFMA, BM=256, N=128, K=768) ----------------
__global__ __launch_bounds__(512, 2) void k_kq(
    const float* __restrict__ rseq, const float* __restrict__ x,
    const unsigned short* __restrict__ keyp, const float* __restrict__ keyb,
    float* __restrict__ partial) {
  __shared__ short sA[2][8192];    // [slot4][256][8]
  __shared__ short sW[2][4096];    // [slot4][128][8]
  const int t = threadIdx.x, w = t >> 6, lane = t & 63, lr = lane & 31, lh = lane >> 5;
  const int mw = w >> 1, nw = w & 1;
  const int m0 = blockIdx.x * 256;

  f32x16 acc[2][2];
#pragma unroll
  for (int mi = 0; mi < 2; ++mi)
#pragma unroll
    for (int ni = 0; ni < 2; ++ni)
#pragma unroll
      for (int e = 0; e < 16; ++e) acc[mi][ni][e] = 0.f;

  float4 ar[4];
  auto issue = [&](int sn, int buf) {
    glds1k(keyp + sn * 4096 + w * 512, &sW[buf][w * 512], lane);
    const float* src; int str, kb;
    if (sn < 16) { src = rseq; str = 512; kb = sn * 32; }
    else         { src = x;    str = 256; kb = (sn - 16) * 32; }
#pragma unroll
    for (int i = 0; i < 4; ++i) {
      int c = t + i * 512, row = c >> 3, kq = c & 7;
      ar[i] = *reinterpret_cast<const float4*>(src + (size_t)(m0 + row) * str + kb + kq * 4);
    }
  };
  auto wr_act = [&](int buf) {
#pragma unroll
    for (int i = 0; i < 4; ++i) {
      int c = t + i * 512, row = c >> 3, kq = c & 7;
      uint2 p;
      p.x = (unsigned)f2bf(ar[i].x) | ((unsigned)f2bf(ar[i].y) << 16);
      p.y = (unsigned)f2bf(ar[i].z) | ((unsigned)f2bf(ar[i].w) << 16);
      *reinterpret_cast<uint2*>(&sA[buf][(kq >> 1) * 2048 + row * 8 + (kq & 1) * 4]) = p;
    }
  };

  issue(0, 0);
  asm volatile("s_waitcnt vmcnt(0)" ::: "memory");
  wr_act(0);
  __syncthreads();

  for (int s = 0; s < 24; ++s) {
    int b = s & 1; bool pf = (s < 23);
    if (pf) issue(s + 1, b ^ 1);
    short8 a[2][2], bb[2][2];
#pragma unroll
    for (int kh = 0; kh < 2; ++kh) {
      int slot = kh * 2 + lh;
#pragma unroll
      for (int mi = 0; mi < 2; ++mi)
        a[kh][mi] = *reinterpret_cast<const short8*>(&sA[b][slot * 2048 + (64 * mw + 32 * mi + lr) * 8]);
#pragma unroll
      for (int ni = 0; ni < 2; ++ni)
        bb[kh][ni] = *reinterpret_cast<const short8*>(&sW[b][slot * 1024 + (64 * nw + 32 * ni + lr) * 8]);
    }
    __builtin_amdgcn_s_setprio(1);
#pragma unroll
    for (int kh = 0; kh < 2; ++kh)
#pragma unroll
      for (int mi = 0; mi < 2; ++mi)
#pragma unroll
        for (int ni = 0; ni < 2; ++ni)
          acc[mi][ni] = mfma16(a[kh][mi], bb[kh][ni], acc[mi][ni]);
    __builtin_amdgcn_s_setprio(0);
    asm volatile("s_waitcnt vmcnt(0)" ::: "memory");
    if (pf) wr_act(b ^ 1);
    __syncthreads();
  }

  // + bias; per-row l2 scale; column partials of l2norm(k)
#pragma unroll
  for (int ni = 0; ni < 2; ++ni) {
    int col = 64 * nw + 32 * ni + lr;
    float bbv = keyb[col];
#pragma unroll
    for (int mi = 0; mi < 2; ++mi)
#pragma unroll
      for (int r = 0; r < 16; ++r) acc[mi][ni][r] += bbv;
  }
  float* red = reinterpret_cast<float*>(sA);   // s2 @0[512], scale @512[256], qp @768[512]
#pragma unroll
  for (int mi = 0; mi < 2; ++mi) {
    int mrow = mw * 2 + mi;
#pragma unroll
    for (int r = 0; r < 16; ++r) {
      float s2 = acc[mi][0][r] * acc[mi][0][r] + acc[mi][1][r] * acc[mi][1][r];
#pragma unroll
      for (int m = 1; m <= 16; m <<= 1) s2 += __shfl_xor(s2, m);
      int rl = (r & 3) + 8 * (r >> 2) + 4 * lh;
      if (lr == r) red[(nw * 8 + mrow) * 32 + rl] = s2;
    }
  }
  __syncthreads();
  if (t < 256) {
    int mrow = t >> 5, rl = t & 31;
    float s = red[(0 * 8 + mrow) * 32 + rl] + red[(8 + mrow) * 32 + rl];
    red[512 + mrow * 32 + rl] = 1.f / fmaxf(sqrtf(s), 1e-8f);
  }
  __syncthreads();
  float p0 = 0.f, p1 = 0.f;
#pragma unroll
  for (int mi = 0; mi < 2; ++mi) {
    int mrow = mw * 2 + mi;
#pragma unroll
    for (int q = 0; q < 4; ++q) {
      float4 sc4 = *reinterpret_cast<float4*>(&red[512 + mrow * 32 + 8 * q + 4 * lh]);
      float sc[4] = {sc4.x, sc4.y, sc4.z, sc4.w};
#pragma unroll
      for (int e = 0; e < 4; ++e) {
        int r = 4 * q + e;
        p0 += acc[mi][0][r] * sc[e];
        p1 += acc[mi][1][r] * sc[e];
      }
    }
  }
  p0 += __shfl_xor(p0, 32);
  p1 += __shfl_xor(p1, 32);
  if (lh == 0) {
    red[768 + mw * 128 + 64 * nw + lr]      = p0;
    red[768 + mw * 128 + 64 * nw + 32 + lr] = p1;
  }
  __syncthreads();
  if (t < 128)
    partial[(size_t)blockIdx.x * 128 + t] =
        red[768 + t] + red[768 + 128 + t] + red[768 + 256 + t] + red[768 + 384 + t];
}

// ---------------- q reduce ----------------
__global__ __launch_bounds__(256) void k_qred(const float* __restrict__ partial,
                                              float* __restrict__ q_ws) {
  int gid = blockIdx.x * 256 + threadIdx.x;   // 0..1023
  int b = gid >> 7, c = gid & 127;
  float s = 0.f;
  for (int i = 0; i < 32; ++i) s += partial[(size_t)(b * 32 + i) * 128 + c];
  q_ws[gid] = s * (1.f / 8192.f);
}

// ---------------- cvec = fftn_b @ fftp_w^T (raw fftp) ----------------
__global__ __launch_bounds__(256) void k_cvec(const float* __restrict__ fb,
                                              const float* __restrict__ fftpw,
                                              float* __restrict__ cvec) {
  int o = blockIdx.x * 256 + threadIdx.x;     // 0..511
  const float* w = fftpw + (size_t)o * 512;
  float s = 0.f;
  for (int k = 0; k < 512; ++k) s += fb[k] * w[k];
  cvec[o] = s;
}

// ---------------- memory (episodic + hebbian) ----------------
__global__ __launch_bounds__(256) void k_mem(
    const float* __restrict__ q_ws, const float* __restrict__ mkeys,
    const float* __restrict__ mvals, const float* __restrict__ hebH,
    const float* __restrict__ rmw, const float* __restrict__ rmb,
    const float* __restrict__ mixl, float* __restrict__ hm) {
  const int b = blockIdx.x, t = threadIdx.x;
  __shared__ float qv[128];
  __shared__ float ssim[256];
  __shared__ float red[256];
  __shared__ float tval[8];
  __shared__ int tidx[8];
  __shared__ float wsm[8];
  __shared__ float vcs[128];

  if (t < 128) qv[t] = q_ws[b * 128 + t];
  __syncthreads();
  red[t] = (t < 128) ? qv[t] * qv[t] : 0.f;
  __syncthreads();
  for (int s = 128; s > 0; s >>= 1) {
    if (t < s) red[t] += red[t + s];
    __syncthreads();
  }
  float qsc = 1.f / fmaxf(sqrtf(red[0]), 1e-8f);
  {
    const float* mk = mkeys + ((size_t)b * 256 + t) * 128;
    float dot = 0.f, ms = 0.f;
    for (int k = 0; k < 128; ++k) { float mv = mk[k]; dot += qv[k] * mv; ms += mv * mv; }
    ssim[t] = dot * qsc / fmaxf(sqrtf(ms), 1e-8f);
  }
  __syncthreads();
  for (int it = 0; it < 8; ++it) {
    if (t < 64) {
      float bv = -1e30f; int bi = 0;
#pragma unroll
      for (int u = 0; u < 4; ++u) {
        int m = t * 4 + u;
        float v = ssim[m];
        if (v > bv) { bv = v; bi = m; }
      }
      for (int off = 32; off; off >>= 1) {
        float ov = __shfl_xor(bv, off, 64);
        int oi = __shfl_xor(bi, off, 64);
        if (ov > bv || (ov == bv && oi < bi)) { bv = ov; bi = oi; }
      }
      if (t == 0) { tval[it] = bv; tidx[it] = bi; ssim[bi] = -1e30f; }
    }
    __syncthreads();
  }
  if (t == 0) {
    float m0 = tval[0], sum = 0.f, e[8];
#pragma unroll
    for (int i = 0; i < 8; ++i) { e[i] = expf(tval[i] - m0); sum += e[i]; }
#pragma unroll
    for (int i = 0; i < 8; ++i) wsm[i] = e[i] / sum;
  }
  __syncthreads();
  float mix = 1.f / (1.f + expf(-mixl[0]));
  if (t < 128) {
    float vh = 0.f;
#pragma unroll
    for (int i = 0; i < 8; ++i) vh += wsm[i] * mvals[((size_t)b * 256 + tidx[i]) * 128 + t];
    float vhb = 0.f;
    const float* H = hebH + (size_t)b * 128 * 128;
    for (int k = 0; k < 128; ++k) vhb += qv[k] * H[k * 128 + t];
    vcs[t] = mix * vh + (1.f - mix) * vhb;
  }
  __syncthreads();
  for (int h = t; h < 512; h += 256) {
    float sum = rmb[h];
    const float* wr = rmw + (size_t)h * 128;
    for (int v = 0; v < 128; ++v) sum += vcs[v] * wr[v];
    hm[b * 512 + h] = sum;
  }
}

// ---------------- fused h_tilde -> LN -> fftp GEMM -> hs (BM=64) ----------------
__global__ __launch_bounds__(512, 2) void k_fused(
    const float* __restrict__ rseq, const float* __restrict__ x,
    const unsigned short* __restrict__ bwp, const unsigned short* __restrict__ uwp,
    const float* __restrict__ ub, const unsigned short* __restrict__ fftps,
    const float* __restrict__ fftpb, const float* __restrict__ fmix,
    const float* __restrict__ cvec, const float* __restrict__ hm,
    float* __restrict__ hs) {
  __shared__ short sH[64 * 512];   // [slot64][64][8]
  __shared__ short sW[2][16384];   // [slot4][512][8]
  __shared__ short sA[2][2048];    // [slot4][64][8]
  const int t = threadIdx.x, w = t >> 6, lane = t & 63, lr = lane & 31, lh = lane >> 5;
  const int mw = w >> 2, nw = w & 3;
  const int m0 = blockIdx.x * 64;
  const int bidx = m0 >> 13;

  f32x16 acc[4];
#pragma unroll
  for (int ni = 0; ni < 4; ++ni)
#pragma unroll
    for (int e = 0; e < 16; ++e) acc[ni][e] = 0.f;

  float4 ar;
  auto issue1 = [&](int sn, int buf) {
    const unsigned short* wsrc = (sn < 16) ? (bwp + sn * 16384) : (uwp + (sn - 16) * 16384);
#pragma unroll
    for (int u = 0; u < 4; ++u)
      glds1k(wsrc + (w * 4 + u) * 512, &sW[buf][(w * 4 + u) * 512], lane);
    const float* src; int str, kb;
    if (sn < 16) { src = rseq; str = 512; kb = sn * 32; }
    else         { src = x;    str = 256; kb = (sn - 16) * 32; }
    int row = t >> 3, kq = t & 7;
    ar = *reinterpret_cast<const float4*>(src + (size_t)(m0 + row) * str + kb + kq * 4);
  };
  auto wr_act = [&](int buf) {
    int row = t >> 3, kq = t & 7;
    uint2 p;
    p.x = (unsigned)f2bf(ar.x) | ((unsigned)f2bf(ar.y) << 16);
    p.y = (unsigned)f2bf(ar.z) | ((unsigned)f2bf(ar.w) << 16);
    *reinterpret_cast<uint2*>(&sA[buf][(kq >> 1) * 512 + row * 8 + (kq & 1) * 4]) = p;
  };

  // ---- GEMM1: h_pre = [r,x] @ [Bw,Uw]^T ----
  issue1(0, 0);
  asm volatile("s_waitcnt vmcnt(0)" ::: "memory");
  wr_act(0);
  __syncthreads();
  for (int s = 0; s < 24; ++s) {
    int b = s & 1; bool pf = (s < 23);
    if (pf) issue1(s + 1, b ^ 1);
    short8 a[2], bb[2][4];
#pragma unroll
    for (int kh = 0; kh < 2; ++kh) {
      int slot = kh * 2 + lh;
      a[kh] = *reinterpret_cast<const short8*>(&sA[b][slot * 512 + (32 * mw + lr) * 8]);
#pragma unroll
      for (int ni = 0; ni < 4; ++ni)
        bb[kh][ni] = *reinterpret_cast<const short8*>(&sW[b][slot * 4096 + (128 * nw + 32 * ni + lr) * 8]);
    }
    __builtin_amdgcn_s_setprio(1);
#pragma unroll
    for (int kh = 0; kh < 2; ++kh)
#pragma unroll
      for (int ni = 0; ni < 4; ++ni)
        acc[ni] = mfma16(a[kh], bb[kh][ni], acc[ni]);
    __builtin_amdgcn_s_setprio(0);
    asm volatile("s_waitcnt vmcnt(0)" ::: "memory");
    if (pf) wr_act(b ^ 1);
    __syncthreads();
  }

  // ---- epilogue1: gelu, LN stats, pack h~, write sH (k-slot layout) ----
#pragma unroll
  for (int ni = 0; ni < 4; ++ni) {
    int col = 128 * nw + 32 * ni + lr;
    float ubc = ub[col];
#pragma unroll
    for (int r = 0; r < 16; ++r) {
      float pre = acc[ni][r] + ubc;
      acc[ni][r] = 0.5f * pre * (1.f + erff(pre * 0.70710678118654752f));
    }
  }
  float* red = reinterpret_cast<float*>(sW);  // red1 @0[256], red2 @256, stats @512[128]
#pragma unroll
  for (int r = 0; r < 16; ++r) {
    float s1 = acc[0][r] + acc[1][r] + acc[2][r] + acc[3][r];
    float s2 = acc[0][r] * acc[0][r] + acc[1][r] * acc[1][r] +
               acc[2][r] * acc[2][r] + acc[3][r] * acc[3][r];
#pragma unroll
    for (int m = 1; m <= 16; m <<= 1) { s1 += __shfl_xor(s1, m); s2 += __shfl_xor(s2, m); }
    int rl = (r & 3) + 8 * (r >> 2) + 4 * lh;
    if (lr == r) { red[(nw * 2 + mw) * 32 + rl] = s1; red[256 + (nw * 2 + mw) * 32 + rl] = s2; }
  }
  __syncthreads();
  if (w == 0) {
    int mw_ = lane >> 5, rl = lane & 31;
    float s1 = 0.f, s2 = 0.f;
#pragma unroll
    for (int n = 0; n < 4; ++n) { s1 += red[(n * 2 + mw_) * 32 + rl]; s2 += red[256 + (n * 2 + mw_) * 32 + rl]; }
    float mean = s1 * (1.f / 512.f);
    float var = s2 * (1.f / 512.f) - mean * mean;
    float rstd = rsqrtf(var + 1e-5f);
    red[512 + (mw_ * 32 + rl) * 2] = mean;
    red[512 + (mw_ * 32 + rl) * 2 + 1] = rstd;
  }
  __syncthreads();
  unsigned htp[4][8];
#pragma unroll
  for (int ni = 0; ni < 4; ++ni)
#pragma unroll
    for (int p = 0; p < 8; ++p)
      htp[ni][p] = (unsigned)f2bf(acc[ni][2 * p]) | ((unsigned)f2bf(acc[ni][2 * p + 1]) << 16);
#pragma unroll
  for (int q = 0; q < 4; ++q) {
    float4 stA = *reinterpret_cast<float4*>(&red[512 + (mw * 32 + 8 * q + 4 * lh) * 2]);
    float4 stB = *reinterpret_cast<float4*>(&red[512 + (mw * 32 + 8 * q + 4 * lh) * 2 + 4]);
    float mean[4] = {stA.x, stA.z, stB.x, stB.z};
    float rstd[4] = {stA.y, stA.w, stB.y, stB.w};
#pragma unroll
    for (int ni = 0; ni < 4; ++ni) {
      int col = 128 * nw + 32 * ni + lr;
#pragma unroll
      for (int e = 0; e < 4; ++e) {
        int r = 4 * q + e;
        float z = (acc[ni][r] - mean[e]) * rstd[e];
        int rloc = 32 * mw + 8 * q + 4 * lh + e;
        sH[(col >> 3) * 512 + rloc * 8 + (col & 7)] = (short)f2bf(z);
      }
    }
  }
#pragma unroll
  for (int ni = 0; ni < 4; ++ni)
#pragma unroll
    for (int e = 0; e < 16; ++e) acc[ni][e] = 0.f;
  __syncthreads();

  // ---- GEMM2: h_norm @ (fftp*g)^T ----
#pragma unroll
  for (int u = 0; u < 4; ++u)
    glds1k(fftps + (w * 4 + u) * 512, &sW[0][(w * 4 + u) * 512], lane);
  asm volatile("s_waitcnt vmcnt(0)" ::: "memory");
  __syncthreads();
  for (int s = 0; s < 16; ++s) {
    int b = s & 1; bool pf = (s < 15);
    if (pf) {
#pragma unroll
      for (int u = 0; u < 4; ++u)
        glds1k(fftps + (s + 1) * 16384 + (w * 4 + u) * 512, &sW[b ^ 1][(w * 4 + u) * 512], lane);
    }
    short8 a[2], bb[2][4];
#pragma unroll
    for (int kh = 0; kh < 2; ++kh) {
      int slot = kh * 2 + lh;
      a[kh] = *reinterpret_cast<const short8*>(&sH[(s * 4 + slot) * 512 + (32 * mw + lr) * 8]);
#pragma unroll
      for (int ni = 0; ni < 4; ++ni)
        bb[kh][ni] = *reinterpret_cast<const short8*>(&sW[b][slot * 4096 + (128 * nw + 32 * ni + lr) * 8]);
    }
    __builtin_amdgcn_s_setprio(1);
#pragma unroll
    for (int kh = 0; kh < 2; ++kh)
#pragma unroll
      for (int ni = 0; ni < 4; ++ni)
        acc[ni] = mfma16(a[kh], bb[kh][ni], acc[ni]);
    __builtin_amdgcn_s_setprio(0);
    asm volatile("s_waitcnt vmcnt(0)" ::: "memory");
    __syncthreads();
  }

  // ---- epilogue2: combine ----
  const float s = 1.f / (1.f + expf(-fmix[0]));
  const float s2f = s * s, oms = 1.f - s;
#pragma unroll
  for (int ni = 0; ni < 4; ++ni) {
    int col = 128 * nw + 32 * ni + lr;
    float base = s2f * cvec[col] + s * fftpb[col] + 0.5f * hm[bidx * 512 + col];
#pragma unroll
    for (int p = 0; p < 8; ++p) {
      unsigned pk = htp[ni][p];
      int r0 = 2 * p;
      int rloc = 32 * mw + (r0 & 3) + 8 * (r0 >> 2) + 4 * lh;
      float o0 = oms * bf2f((unsigned short)(pk & 0xFFFF)) + s2f * acc[ni][r0] + base;
      float o1 = oms * bf2f((unsigned short)(pk >> 16)) + s2f * acc[ni][r0 + 1] + base;
      hs[(size_t)(m0 + rloc) * 512 + col] = o0;
      hs[(size_t)(m0 + rloc + 1) * 512 + col] = o1;
    }
  }
}

extern "C" void kernel_launch(void* const* d_in, const int* in_sizes, int n_in,
                              void* d_out, int out_size, void* d_ws, size_t ws_size,
                              hipStream_t stream) {
  (void)in_sizes; (void)n_in; (void)out_size; (void)ws_size;
  const float* x     = (const float*)d_in[0];
  const float* Wxw   = (const float*)d_in[1];
  const float* Wxb   = (const float*)d_in[2];
  const float* resa  = (const float*)d_in[4];
  const float* Bw    = (const float*)d_in[6];
  const float* Uw    = (const float*)d_in[7];
  const float* Ub    = (const float*)d_in[8];
  const float* fg    = (const float*)d_in[9];
  const float* fb    = (const float*)d_in[10];
  const float* fftpw = (const float*)d_in[11];
  const float* fftpb = (const float*)d_in[12];
  const float* fmix  = (const float*)d_in[13];
  const float* mixl  = (const float*)d_in[14];
  const float* keyw  = (const float*)d_in[15];
  const float* keyb  = (const float*)d_in[16];
  const float* rmw   = (const float*)d_in[19];
  const float* rmb   = (const float*)d_in[20];
  const float* rng   = (const float*)d_in[21];
  const float* rnb   = (const float*)d_in[22];
  const float* mkeys = (const float*)d_in[23];
  const float* mvals = (const float*)d_in[24];
  const float* hebH  = (const float*)d_in[25];

  float* outp = (float*)d_out;
  float* hs   = outp;                               // (B,T,512)
  float* rout = outp + (size_t)65536 * 512;         // (B,T,512)

  unsigned short* wsu = (unsigned short*)d_ws;
  unsigned short* wxp    = wsu;                     // 131072
  unsigned short* keyp   = wsu + 131072;            // 98304
  unsigned short* bwp    = wsu + 229376;            // 262144
  unsigned short* uwp    = wsu + 491520;            // 131072
  unsigned short* fftps  = wsu + 622592;            // 262144
  float* wsf     = (float*)d_ws;
  float* partial = wsf + 524288;                    // 256*128
  float* q_ws    = wsf + 589824;                    // 1024
  float* hm      = wsf + 590848;                    // 4096
  float* cvec    = wsf + 594944;                    // 512

  k_wconv<<<3456, 256, 0, stream>>>(Wxw, keyw, Bw, Uw, fftpw, fg,
                                    wxp, keyp, bwp, uwp, fftps);
  k_cvec <<<2,    256, 0, stream>>>(fb, fftpw, cvec);
  k_rseq <<<1024, 512, 0, stream>>>(x, wxp, Wxb, resa, rng, rnb, rout);
  k_kq   <<<256,  512, 0, stream>>>(rout, x, keyp, keyb, partial);
  k_qred <<<4,    256, 0, stream>>>(partial, q_ws);
  k_mem  <<<8,    256, 0, stream>>>(q_ws, mkeys, mvals, hebH, rmw, rmb, mixl, hm);
  k_fused<<<1024, 512, 0, stream>>>(rout, x, bwp, uwp, Ub, fftps, fftpb,
                                    fmix, cvec, hm, hs);
}

// Round 5
// 411.121 us; speedup vs baseline: 2.6393x; 1.1306x over previous
//
#include <hip/hip_runtime.h>
#include <cmath>

// CRSDCell bf16-MFMA pipeline, round 5: reg-staged weights (no weight LDS),
// lgkmcnt-only barriers, deep act pipeline.
//  - Weights pre-packed chunk-major P[k0][slot4][n][8] (k=k0*32+slot*8+i) and
//    L2-resident; each wave loads its own B-frags global->VGPR 1 step ahead.
//  - Wave decomp: 8 n-waves x 64 cols, BM=64 rows -> no B redundancy in block.
//  - Acts: global->reg at step s for s+2, ds_write at s+1 (T14 split),
//    sA dbuf 2x4KB. Barrier = s_waitcnt lgkmcnt(0) + s_barrier (+sched pin):
//    in-flight global loads survive the barrier.
//  - GEMM2 (h_norm @ fftp^T): sH read-only -> NO barriers, waves free-run.
// FFT folds exactly: irfft(rfft(h)*s) = s*h. h_prev=r_prev=0 kills Wh/A terms.

typedef __attribute__((ext_vector_type(8)))  short short8;
typedef __attribute__((ext_vector_type(16))) float f32x16;

__device__ __forceinline__ unsigned short f2bf(float f) {
  union { float f; unsigned u; } v; v.f = f;
  unsigned r = v.u + 0x7FFF + ((v.u >> 16) & 1);   // RTNE
  return (unsigned short)(r >> 16);
}
__device__ __forceinline__ float bf2f(unsigned short h) {
  union { unsigned u; float f; } v; v.u = ((unsigned)h) << 16; return v.f;
}
__device__ __forceinline__ f32x16 mfma16(short8 a, short8 b, f32x16 c) {
  return __builtin_amdgcn_mfma_f32_32x32x16_bf16(a, b, c, 0, 0, 0);
}
// copy 1KB: 64 lanes x 16B, contiguous global -> linear LDS (k_kq only)
__device__ __forceinline__ void glds1k(const unsigned short* g, short* l, int lane) {
  typedef const __attribute__((address_space(1))) unsigned int* gp_t;
  typedef __attribute__((address_space(3))) unsigned int* lp_t;
  __builtin_amdgcn_global_load_lds((gp_t)(const void*)(g + lane * 8),
                                   (lp_t)(void*)l, 16, 0, 0);
}
__device__ __forceinline__ void barrier_lgkm() {
  asm volatile("s_waitcnt lgkmcnt(0)" ::: "memory");
  __builtin_amdgcn_s_barrier();
  __builtin_amdgcn_sched_barrier(0);
}

// ---------------- weight convert + pack ----------------
// packed offset for (n,k) in [N][K]: (k>>5)*N*32 + ((k>>3)&3)*N*8 + n*8 + (k&7)
__global__ __launch_bounds__(256) void k_wconv(
    const float* __restrict__ wx, const float* __restrict__ key,
    const float* __restrict__ bw, const float* __restrict__ uw,
    const float* __restrict__ fftpw, const float* __restrict__ fg,
    unsigned short* __restrict__ wxp, unsigned short* __restrict__ keyp,
    unsigned short* __restrict__ bwp, unsigned short* __restrict__ uwp,
    unsigned short* __restrict__ fftps) {
  int i = blockIdx.x * 256 + threadIdx.x;
  if (i >= 884736) return;
  float v; int n, k, N; unsigned short* dst;
  if (i < 131072)      { int j = i;          N = 512; k = j & 255; n = j >> 8; v = wx[j];  dst = wxp; }
  else if (i < 229376) { int j = i - 131072; N = 128; k = j % 768; n = j / 768; v = key[j]; dst = keyp; }
  else if (i < 491520) { int j = i - 229376; N = 512; k = j & 511; n = j >> 9; v = bw[j];  dst = bwp; }
  else if (i < 622592) { int j = i - 491520; N = 512; k = j & 255; n = j >> 8; v = uw[j];  dst = uwp; }
  else                 { int j = i - 622592; N = 512; k = j & 511; n = j >> 9; v = fftpw[j] * fg[k]; dst = fftps; }
  dst[(k >> 5) * (N * 32) + ((k >> 3) & 3) * (N * 8) + n * 8 + (k & 7)] = f2bf(v);
}

// ---------------- K1: r_seq (MFMA, BM=64, N=512, K=256, 8 n-waves) ----------
__global__ __launch_bounds__(512, 2) void k_rseq(
    const float* __restrict__ x, const unsigned short* __restrict__ wxp,
    const float* __restrict__ wxb, const float* __restrict__ resa,
    const float* __restrict__ rng, const float* __restrict__ rnb,
    float* __restrict__ rout) {
  __shared__ short sA[2][2048];    // [slot4][64][8]
  __shared__ float red[1152];
  const int t = threadIdx.x, w = t >> 6, lane = t & 63, lr = lane & 31, lh = lane >> 5;
  const int m0 = blockIdx.x * 64;

  f32x16 acc[2][2];
#pragma unroll
  for (int mi = 0; mi < 2; ++mi)
#pragma unroll
    for (int ni = 0; ni < 2; ++ni)
#pragma unroll
      for (int e = 0; e < 16; ++e) acc[mi][ni][e] = 0.f;

  short8 b0[4], b1[4];
  float4 a0, a1;

  auto loadB = [&](int sn, short8 (&bd)[4]) {
#pragma unroll
    for (int kh = 0; kh < 2; ++kh)
#pragma unroll
      for (int ni = 0; ni < 2; ++ni)
        bd[kh * 2 + ni] = *reinterpret_cast<const short8*>(
            wxp + (size_t)sn * 16384 + (kh * 2 + lh) * 4096 + (64 * w + 32 * ni + lr) * 8);
  };
  auto loadAct = [&](int sn, float4& ad) {
    int row = t >> 3, kq = t & 7;
    ad = *reinterpret_cast<const float4*>(x + (size_t)(m0 + row) * 256 + sn * 32 + kq * 4);
  };
  auto writeAct = [&](const float4& ad, int buf) {
    int row = t >> 3, kq = t & 7;
    uint2 p;
    p.x = (unsigned)f2bf(ad.x) | ((unsigned)f2bf(ad.y) << 16);
    p.y = (unsigned)f2bf(ad.z) | ((unsigned)f2bf(ad.w) << 16);
    *reinterpret_cast<uint2*>(&sA[buf][(kq >> 1) * 512 + row * 8 + (kq & 1) * 4]) = p;
  };
  auto mfstep = [&](int buf, short8 (&bc)[4]) {
    short8 af[4];
#pragma unroll
    for (int kh = 0; kh < 2; ++kh)
#pragma unroll
      for (int mi = 0; mi < 2; ++mi)
        af[kh * 2 + mi] = *reinterpret_cast<const short8*>(
            &sA[buf][(kh * 2 + lh) * 512 + (32 * mi + lr) * 8]);
    __builtin_amdgcn_s_setprio(1);
#pragma unroll
    for (int kh = 0; kh < 2; ++kh)
#pragma unroll
      for (int mi = 0; mi < 2; ++mi)
#pragma unroll
        for (int ni = 0; ni < 2; ++ni)
          acc[mi][ni] = mfma16(af[kh * 2 + mi], bc[kh * 2 + ni], acc[mi][ni]);
    __builtin_amdgcn_s_setprio(0);
  };

  const int NS = 8;
  loadAct(0, a0);
  loadB(0, b0);
  loadAct(1, a1);
  writeAct(a0, 0);
  barrier_lgkm();
  for (int s = 0; s < NS; s += 2) {
    if (s + 1 < NS) loadB(s + 1, b1);
    if (s + 2 < NS) loadAct(s + 2, a0);
    mfstep(s & 1, b0);
    if (s + 1 < NS) writeAct(a1, (s + 1) & 1);
    barrier_lgkm();
    if (s + 2 < NS) loadB(s + 2, b0);
    if (s + 3 < NS) loadAct(s + 3, a1);
    mfstep((s + 1) & 1, b1);
    if (s + 2 < NS) writeAct(a0, s & 1);
    barrier_lgkm();
  }

  // epilogue: z = (1-alpha)*tanh(acc+b), LN over 512 cols
#pragma unroll
  for (int ni = 0; ni < 2; ++ni) {
    int col = 64 * w + 32 * ni + lr;
    float al = 1.f / (1.f + expf(-resa[col >> 7]));
    float oma = 1.f - al, bbv = wxb[col];
#pragma unroll
    for (int mi = 0; mi < 2; ++mi)
#pragma unroll
      for (int r = 0; r < 16; ++r)
        acc[mi][ni][r] = oma * tanhf(acc[mi][ni][r] + bbv);
  }
#pragma unroll
  for (int mi = 0; mi < 2; ++mi)
#pragma unroll
    for (int r = 0; r < 16; ++r) {
      float s1 = acc[mi][0][r] + acc[mi][1][r];
      float s2 = acc[mi][0][r] * acc[mi][0][r] + acc[mi][1][r] * acc[mi][1][r];
#pragma unroll
      for (int m = 1; m <= 16; m <<= 1) { s1 += __shfl_xor(s1, m); s2 += __shfl_xor(s2, m); }
      int rl = (r & 3) + 8 * (r >> 2) + 4 * lh;
      if (lr == r) { red[(w * 2 + mi) * 32 + rl] = s1; red[512 + (w * 2 + mi) * 32 + rl] = s2; }
    }
  __syncthreads();
  if (t < 64) {
    int mi = t >> 5, rl = t & 31;
    float s1 = 0.f, s2 = 0.f;
#pragma unroll
    for (int n = 0; n < 8; ++n) { s1 += red[(n * 2 + mi) * 32 + rl]; s2 += red[512 + (n * 2 + mi) * 32 + rl]; }
    float mean = s1 * (1.f / 512.f);
    float var = s2 * (1.f / 512.f) - mean * mean;
    float rstd = rsqrtf(var + 1e-5f);
    red[1024 + t * 2] = mean;
    red[1024 + t * 2 + 1] = rstd;
  }
  __syncthreads();
#pragma unroll
  for (int q = 0; q < 4; ++q)
#pragma unroll
    for (int mi = 0; mi < 2; ++mi) {
      float4 stA = *reinterpret_cast<float4*>(&red[1024 + (32 * mi + 8 * q + 4 * lh) * 2]);
      float4 stB = *reinterpret_cast<float4*>(&red[1024 + (32 * mi + 8 * q + 4 * lh) * 2 + 4]);
      float mean[4] = {stA.x, stA.z, stB.x, stB.z};
      float rstd[4] = {stA.y, stA.w, stB.y, stB.w};
#pragma unroll
      for (int ni = 0; ni < 2; ++ni) {
        int col = 64 * w + 32 * ni + lr;
        float g = rng[col], bbv = rnb[col];
#pragma unroll
        for (int e = 0; e < 4; ++e) {
          int r = 4 * q + e;
          int grow = m0 + 32 * mi + 8 * q + 4 * lh + e;
          rout[(size_t)grow * 512 + col] = (acc[mi][ni][r] - mean[e]) * rstd[e] * g + bbv;
        }
      }
    }
}

// ---------------- K2: k + q partials (MFMA, BM=256, N=128, K=768) ----------------
__global__ __launch_bounds__(512, 2) void k_kq(
    const float* __restrict__ rseq, const float* __restrict__ x,
    const unsigned short* __restrict__ keyp, const float* __restrict__ keyb,
    float* __restrict__ partial) {
  __shared__ short sA[2][8192];    // [slot4][256][8]
  __shared__ short sW[2][4096];    // [slot4][128][8]
  const int t = threadIdx.x, w = t >> 6, lane = t & 63, lr = lane & 31, lh = lane >> 5;
  const int mw = w >> 1, nw = w & 1;
  const int m0 = blockIdx.x * 256;

  f32x16 acc[2][2];
#pragma unroll
  for (int mi = 0; mi < 2; ++mi)
#pragma unroll
    for (int ni = 0; ni < 2; ++ni)
#pragma unroll
      for (int e = 0; e < 16; ++e) acc[mi][ni][e] = 0.f;

  float4 ar[4];
  auto issue = [&](int sn, int buf) {
    glds1k(keyp + sn * 4096 + w * 512, &sW[buf][w * 512], lane);
    const float* src; int str, kb;
    if (sn < 16) { src = rseq; str = 512; kb = sn * 32; }
    else         { src = x;    str = 256; kb = (sn - 16) * 32; }
#pragma unroll
    for (int i = 0; i < 4; ++i) {
      int c = t + i * 512, row = c >> 3, kq = c & 7;
      ar[i] = *reinterpret_cast<const float4*>(src + (size_t)(m0 + row) * str + kb + kq * 4);
    }
  };
  auto wr_act = [&](int buf) {
#pragma unroll
    for (int i = 0; i < 4; ++i) {
      int c = t + i * 512, row = c >> 3, kq = c & 7;
      uint2 p;
      p.x = (unsigned)f2bf(ar[i].x) | ((unsigned)f2bf(ar[i].y) << 16);
      p.y = (unsigned)f2bf(ar[i].z) | ((unsigned)f2bf(ar[i].w) << 16);
      *reinterpret_cast<uint2*>(&sA[buf][(kq >> 1) * 2048 + row * 8 + (kq & 1) * 4]) = p;
    }
  };

  issue(0, 0);
  asm volatile("s_waitcnt vmcnt(0)" ::: "memory");
  wr_act(0);
  __syncthreads();

  for (int s = 0; s < 24; ++s) {
    int b = s & 1; bool pf = (s < 23);
    if (pf) issue(s + 1, b ^ 1);
    short8 a[2][2], bb[2][2];
#pragma unroll
    for (int kh = 0; kh < 2; ++kh) {
      int slot = kh * 2 + lh;
#pragma unroll
      for (int mi = 0; mi < 2; ++mi)
        a[kh][mi] = *reinterpret_cast<const short8*>(&sA[b][slot * 2048 + (64 * mw + 32 * mi + lr) * 8]);
#pragma unroll
      for (int ni = 0; ni < 2; ++ni)
        bb[kh][ni] = *reinterpret_cast<const short8*>(&sW[b][slot * 1024 + (64 * nw + 32 * ni + lr) * 8]);
    }
    __builtin_amdgcn_s_setprio(1);
#pragma unroll
    for (int kh = 0; kh < 2; ++kh)
#pragma unroll
      for (int mi = 0; mi < 2; ++mi)
#pragma unroll
        for (int ni = 0; ni < 2; ++ni)
          acc[mi][ni] = mfma16(a[kh][mi], bb[kh][ni], acc[mi][ni]);
    __builtin_amdgcn_s_setprio(0);
    asm volatile("s_waitcnt vmcnt(0)" ::: "memory");
    if (pf) wr_act(b ^ 1);
    __syncthreads();
  }

  // + bias; per-row l2 scale; column partials of l2norm(k)
#pragma unroll
  for (int ni = 0; ni < 2; ++ni) {
    int col = 64 * nw + 32 * ni + lr;
    float bbv = keyb[col];
#pragma unroll
    for (int mi = 0; mi < 2; ++mi)
#pragma unroll
      for (int r = 0; r < 16; ++r) acc[mi][ni][r] += bbv;
  }
  float* red = reinterpret_cast<float*>(sA);   // s2 @0[512], scale @512[256], qp @768[512]
#pragma unroll
  for (int mi = 0; mi < 2; ++mi) {
    int mrow = mw * 2 + mi;
#pragma unroll
    for (int r = 0; r < 16; ++r) {
      float s2 = acc[mi][0][r] * acc[mi][0][r] + acc[mi][1][r] * acc[mi][1][r];
#pragma unroll
      for (int m = 1; m <= 16; m <<= 1) s2 += __shfl_xor(s2, m);
      int rl = (r & 3) + 8 * (r >> 2) + 4 * lh;
      if (lr == r) red[(nw * 8 + mrow) * 32 + rl] = s2;
    }
  }
  __syncthreads();
  if (t < 256) {
    int mrow = t >> 5, rl = t & 31;
    float s = red[(0 * 8 + mrow) * 32 + rl] + red[(8 + mrow) * 32 + rl];
    red[512 + mrow * 32 + rl] = 1.f / fmaxf(sqrtf(s), 1e-8f);
  }
  __syncthreads();
  float p0 = 0.f, p1 = 0.f;
#pragma unroll
  for (int mi = 0; mi < 2; ++mi) {
    int mrow = mw * 2 + mi;
#pragma unroll
    for (int q = 0; q < 4; ++q) {
      float4 sc4 = *reinterpret_cast<float4*>(&red[512 + mrow * 32 + 8 * q + 4 * lh]);
      float sc[4] = {sc4.x, sc4.y, sc4.z, sc4.w};
#pragma unroll
      for (int e = 0; e < 4; ++e) {
        int r = 4 * q + e;
        p0 += acc[mi][0][r] * sc[e];
        p1 += acc[mi][1][r] * sc[e];
      }
    }
  }
  p0 += __shfl_xor(p0, 32);
  p1 += __shfl_xor(p1, 32);
  if (lh == 0) {
    red[768 + mw * 128 + 64 * nw + lr]      = p0;
    red[768 + mw * 128 + 64 * nw + 32 + lr] = p1;
  }
  __syncthreads();
  if (t < 128)
    partial[(size_t)blockIdx.x * 128 + t] =
        red[768 + t] + red[768 + 128 + t] + red[768 + 256 + t] + red[768 + 384 + t];
}

// ---------------- q reduce ----------------
__global__ __launch_bounds__(256) void k_qred(const float* __restrict__ partial,
                                              float* __restrict__ q_ws) {
  int gid = blockIdx.x * 256 + threadIdx.x;   // 0..1023
  int b = gid >> 7, c = gid & 127;
  float s = 0.f;
  for (int i = 0; i < 32; ++i) s += partial[(size_t)(b * 32 + i) * 128 + c];
  q_ws[gid] = s * (1.f / 8192.f);
}

// ---------------- cvec = fftn_b @ fftp_w^T (raw fftp) ----------------
__global__ __launch_bounds__(256) void k_cvec(const float* __restrict__ fb,
                                              const float* __restrict__ fftpw,
                                              float* __restrict__ cvec) {
  int o = blockIdx.x * 256 + threadIdx.x;     // 0..511
  const float* w = fftpw + (size_t)o * 512;
  float s = 0.f;
  for (int k = 0; k < 512; ++k) s += fb[k] * w[k];
  cvec[o] = s;
}

// ---------------- memory (episodic + hebbian) ----------------
__global__ __launch_bounds__(256) void k_mem(
    const float* __restrict__ q_ws, const float* __restrict__ mkeys,
    const float* __restrict__ mvals, const float* __restrict__ hebH,
    const float* __restrict__ rmw, const float* __restrict__ rmb,
    const float* __restrict__ mixl, float* __restrict__ hm) {
  const int b = blockIdx.x, t = threadIdx.x;
  __shared__ float qv[128];
  __shared__ float ssim[256];
  __shared__ float red[256];
  __shared__ float tval[8];
  __shared__ int tidx[8];
  __shared__ float wsm[8];
  __shared__ float vcs[128];

  if (t < 128) qv[t] = q_ws[b * 128 + t];
  __syncthreads();
  red[t] = (t < 128) ? qv[t] * qv[t] : 0.f;
  __syncthreads();
  for (int s = 128; s > 0; s >>= 1) {
    if (t < s) red[t] += red[t + s];
    __syncthreads();
  }
  float qsc = 1.f / fmaxf(sqrtf(red[0]), 1e-8f);
  {
    const float* mk = mkeys + ((size_t)b * 256 + t) * 128;
    float dot = 0.f, ms = 0.f;
    for (int k = 0; k < 128; ++k) { float mv = mk[k]; dot += qv[k] * mv; ms += mv * mv; }
    ssim[t] = dot * qsc / fmaxf(sqrtf(ms), 1e-8f);
  }
  __syncthreads();
  for (int it = 0; it < 8; ++it) {
    if (t < 64) {
      float bv = -1e30f; int bi = 0;
#pragma unroll
      for (int u = 0; u < 4; ++u) {
        int m = t * 4 + u;
        float v = ssim[m];
        if (v > bv) { bv = v; bi = m; }
      }
      for (int off = 32; off; off >>= 1) {
        float ov = __shfl_xor(bv, off, 64);
        int oi = __shfl_xor(bi, off, 64);
        if (ov > bv || (ov == bv && oi < bi)) { bv = ov; bi = oi; }
      }
      if (t == 0) { tval[it] = bv; tidx[it] = bi; ssim[bi] = -1e30f; }
    }
    __syncthreads();
  }
  if (t == 0) {
    float m0 = tval[0], sum = 0.f, e[8];
#pragma unroll
    for (int i = 0; i < 8; ++i) { e[i] = expf(tval[i] - m0); sum += e[i]; }
#pragma unroll
    for (int i = 0; i < 8; ++i) wsm[i] = e[i] / sum;
  }
  __syncthreads();
  float mix = 1.f / (1.f + expf(-mixl[0]));
  if (t < 128) {
    float vh = 0.f;
#pragma unroll
    for (int i = 0; i < 8; ++i) vh += wsm[i] * mvals[((size_t)b * 256 + tidx[i]) * 128 + t];
    float vhb = 0.f;
    const float* H = hebH + (size_t)b * 128 * 128;
    for (int k = 0; k < 128; ++k) vhb += qv[k] * H[k * 128 + t];
    vcs[t] = mix * vh + (1.f - mix) * vhb;
  }
  __syncthreads();
  for (int h = t; h < 512; h += 256) {
    float sum = rmb[h];
    const float* wr = rmw + (size_t)h * 128;
    for (int v = 0; v < 128; ++v) sum += vcs[v] * wr[v];
    hm[b * 512 + h] = sum;
  }
}

// ---------------- fused h_tilde -> LN -> fftp GEMM -> hs (BM=64, 8 n-waves) --
__global__ __launch_bounds__(512, 2) void k_fused(
    const float* __restrict__ rseq, const float* __restrict__ x,
    const unsigned short* __restrict__ bwp, const unsigned short* __restrict__ uwp,
    const float* __restrict__ ub, const unsigned short* __restrict__ fftps,
    const float* __restrict__ fftpb, const float* __restrict__ fmix,
    const float* __restrict__ cvec, const float* __restrict__ hm,
    float* __restrict__ hs) {
  __shared__ short sH[64 * 512];   // [slot64][64][8]  (64KB)
  __shared__ short sA[2][2048];    // [slot4][64][8]   (8KB)
  __shared__ float red[1152];
  const int t = threadIdx.x, w = t >> 6, lane = t & 63, lr = lane & 31, lh = lane >> 5;
  const int m0 = blockIdx.x * 64;
  const int bidx = m0 >> 13;

  f32x16 acc[2][2];
#pragma unroll
  for (int mi = 0; mi < 2; ++mi)
#pragma unroll
    for (int ni = 0; ni < 2; ++ni)
#pragma unroll
      for (int e = 0; e < 16; ++e) acc[mi][ni][e] = 0.f;

  short8 b0[4], b1[4];
  float4 a0, a1;

  auto loadB1 = [&](int sn, short8 (&bd)[4]) {
    const unsigned short* wp = (sn < 16) ? (bwp + (size_t)sn * 16384)
                                         : (uwp + (size_t)(sn - 16) * 16384);
#pragma unroll
    for (int kh = 0; kh < 2; ++kh)
#pragma unroll
      for (int ni = 0; ni < 2; ++ni)
        bd[kh * 2 + ni] = *reinterpret_cast<const short8*>(
            wp + (kh * 2 + lh) * 4096 + (64 * w + 32 * ni + lr) * 8);
  };
  auto loadAct = [&](int sn, float4& ad) {
    const float* src; int str, kb;
    if (sn < 16) { src = rseq; str = 512; kb = sn * 32; }
    else         { src = x;    str = 256; kb = (sn - 16) * 32; }
    int row = t >> 3, kq = t & 7;
    ad = *reinterpret_cast<const float4*>(src + (size_t)(m0 + row) * str + kb + kq * 4);
  };
  auto writeAct = [&](const float4& ad, int buf) {
    int row = t >> 3, kq = t & 7;
    uint2 p;
    p.x = (unsigned)f2bf(ad.x) | ((unsigned)f2bf(ad.y) << 16);
    p.y = (unsigned)f2bf(ad.z) | ((unsigned)f2bf(ad.w) << 16);
    *reinterpret_cast<uint2*>(&sA[buf][(kq >> 1) * 512 + row * 8 + (kq & 1) * 4]) = p;
  };
  auto mfstep1 = [&](int buf, short8 (&bc)[4]) {
    short8 af[4];
#pragma unroll
    for (int kh = 0; kh < 2; ++kh)
#pragma unroll
      for (int mi = 0; mi < 2; ++mi)
        af[kh * 2 + mi] = *reinterpret_cast<const short8*>(
            &sA[buf][(kh * 2 + lh) * 512 + (32 * mi + lr) * 8]);
    __builtin_amdgcn_s_setprio(1);
#pragma unroll
    for (int kh = 0; kh < 2; ++kh)
#pragma unroll
      for (int mi = 0; mi < 2; ++mi)
#pragma unroll
        for (int ni = 0; ni < 2; ++ni)
          acc[mi][ni] = mfma16(af[kh * 2 + mi], bc[kh * 2 + ni], acc[mi][ni]);
    __builtin_amdgcn_s_setprio(0);
  };

  // ---- GEMM1: h_pre = [r,x] @ [Bw,Uw]^T, 24 K-steps ----
  const int NS = 24;
  loadAct(0, a0);
  loadB1(0, b0);
  loadAct(1, a1);
  writeAct(a0, 0);
  barrier_lgkm();
  for (int s = 0; s < NS; s += 2) {
    if (s + 1 < NS) loadB1(s + 1, b1);
    if (s + 2 < NS) loadAct(s + 2, a0);
    mfstep1(s & 1, b0);
    if (s + 1 < NS) writeAct(a1, (s + 1) & 1);
    barrier_lgkm();
    if (s + 2 < NS) loadB1(s + 2, b0);
    if (s + 3 < NS) loadAct(s + 3, a1);
    mfstep1((s + 1) & 1, b1);
    if (s + 2 < NS) writeAct(a0, s & 1);
    barrier_lgkm();
  }

  // ---- epilogue1: gelu, LN stats, pack h~, write sH (k-slot layout) ----
#pragma unroll
  for (int mi = 0; mi < 2; ++mi)
#pragma unroll
    for (int ni = 0; ni < 2; ++ni) {
      int col = 64 * w + 32 * ni + lr;
      float ubc = ub[col];
#pragma unroll
      for (int r = 0; r < 16; ++r) {
        float pre = acc[mi][ni][r] + ubc;
        acc[mi][ni][r] = 0.5f * pre * (1.f + erff(pre * 0.70710678118654752f));
      }
    }
#pragma unroll
  for (int mi = 0; mi < 2; ++mi)
#pragma unroll
    for (int r = 0; r < 16; ++r) {
      float s1 = acc[mi][0][r] + acc[mi][1][r];
      float s2 = acc[mi][0][r] * acc[mi][0][r] + acc[mi][1][r] * acc[mi][1][r];
#pragma unroll
      for (int m = 1; m <= 16; m <<= 1) { s1 += __shfl_xor(s1, m); s2 += __shfl_xor(s2, m); }
      int rl = (r & 3) + 8 * (r >> 2) + 4 * lh;
      if (lr == r) { red[(w * 2 + mi) * 32 + rl] = s1; red[512 + (w * 2 + mi) * 32 + rl] = s2; }
    }
  __syncthreads();
  if (t < 64) {
    int mi = t >> 5, rl = t & 31;
    float s1 = 0.f, s2 = 0.f;
#pragma unroll
    for (int n = 0; n < 8; ++n) { s1 += red[(n * 2 + mi) * 32 + rl]; s2 += red[512 + (n * 2 + mi) * 32 + rl]; }
    float mean = s1 * (1.f / 512.f);
    float var = s2 * (1.f / 512.f) - mean * mean;
    float rstd = rsqrtf(var + 1e-5f);
    red[1024 + t * 2] = mean;
    red[1024 + t * 2 + 1] = rstd;
  }
  __syncthreads();
  unsigned htp[2][2][8];
#pragma unroll
  for (int mi = 0; mi < 2; ++mi)
#pragma unroll
    for (int ni = 0; ni < 2; ++ni)
#pragma unroll
      for (int p = 0; p < 8; ++p)
        htp[mi][ni][p] = (unsigned)f2bf(acc[mi][ni][2 * p]) |
                         ((unsigned)f2bf(acc[mi][ni][2 * p + 1]) << 16);
#pragma unroll
  for (int q = 0; q < 4; ++q)
#pragma unroll
    for (int mi = 0; mi < 2; ++mi) {
      float4 stA = *reinterpret_cast<float4*>(&red[1024 + (32 * mi + 8 * q + 4 * lh) * 2]);
      float4 stB = *reinterpret_cast<float4*>(&red[1024 + (32 * mi + 8 * q + 4 * lh) * 2 + 4]);
      float mean[4] = {stA.x, stA.z, stB.x, stB.z};
      float rstd[4] = {stA.y, stA.w, stB.y, stB.w};
#pragma unroll
      for (int ni = 0; ni < 2; ++ni) {
        int col = 64 * w + 32 * ni + lr;
#pragma unroll
        for (int e = 0; e < 4; ++e) {
          int r = 4 * q + e;
          float z = (acc[mi][ni][r] - mean[e]) * rstd[e];
          int rloc = 32 * mi + 8 * q + 4 * lh + e;
          sH[(col >> 3) * 512 + rloc * 8 + (col & 7)] = (short)f2bf(z);
        }
      }
    }
#pragma unroll
  for (int mi = 0; mi < 2; ++mi)
#pragma unroll
    for (int ni = 0; ni < 2; ++ni)
#pragma unroll
      for (int e = 0; e < 16; ++e) acc[mi][ni][e] = 0.f;
  __syncthreads();

  // ---- GEMM2: h_norm @ (fftp*g)^T, 16 K-steps, NO barriers ----
  auto loadB2 = [&](int sn, short8 (&bd)[4]) {
#pragma unroll
    for (int kh = 0; kh < 2; ++kh)
#pragma unroll
      for (int ni = 0; ni < 2; ++ni)
        bd[kh * 2 + ni] = *reinterpret_cast<const short8*>(
            fftps + (size_t)sn * 16384 + (kh * 2 + lh) * 4096 + (64 * w + 32 * ni + lr) * 8);
  };
  auto mfstep2 = [&](int sn, short8 (&bc)[4]) {
    short8 af[4];
#pragma unroll
    for (int kh = 0; kh < 2; ++kh)
#pragma unroll
      for (int mi = 0; mi < 2; ++mi)
        af[kh * 2 + mi] = *reinterpret_cast<const short8*>(
            &sH[(sn * 4 + kh * 2 + lh) * 512 + (32 * mi + lr) * 8]);
    __builtin_amdgcn_s_setprio(1);
#pragma unroll
    for (int kh = 0; kh < 2; ++kh)
#pragma unroll
      for (int mi = 0; mi < 2; ++mi)
#pragma unroll
        for (int ni = 0; ni < 2; ++ni)
          acc[mi][ni] = mfma16(af[kh * 2 + mi], bc[kh * 2 + ni], acc[mi][ni]);
    __builtin_amdgcn_s_setprio(0);
  };
  loadB2(0, b0);
  for (int s = 0; s < 16; s += 2) {
    loadB2(s + 1, b1);
    mfstep2(s, b0);
    if (s + 2 < 16) loadB2(s + 2, b0);
    mfstep2(s + 1, b1);
  }

  // ---- epilogue2: combine ----
  const float sg = 1.f / (1.f + expf(-fmix[0]));
  const float s2f = sg * sg, oms = 1.f - sg;
#pragma unroll
  for (int mi = 0; mi < 2; ++mi)
#pragma unroll
    for (int ni = 0; ni < 2; ++ni) {
      int col = 64 * w + 32 * ni + lr;
      float base = s2f * cvec[col] + sg * fftpb[col] + 0.5f * hm[bidx * 512 + col];
#pragma unroll
      for (int p = 0; p < 8; ++p) {
        unsigned pk = htp[mi][ni][p];
        int r0 = 2 * p;
        int rloc = 32 * mi + (r0 & 3) + 8 * (r0 >> 2) + 4 * lh;
        float o0 = oms * bf2f((unsigned short)(pk & 0xFFFF)) + s2f * acc[mi][ni][r0] + base;
        float o1 = oms * bf2f((unsigned short)(pk >> 16)) + s2f * acc[mi][ni][r0 + 1] + base;
        hs[(size_t)(m0 + rloc) * 512 + col] = o0;
        hs[(size_t)(m0 + rloc + 1) * 512 + col] = o1;
      }
    }
}

extern "C" void kernel_launch(void* const* d_in, const int* in_sizes, int n_in,
                              void* d_out, int out_size, void* d_ws, size_t ws_size,
                              hipStream_t stream) {
  (void)in_sizes; (void)n_in; (void)out_size; (void)ws_size;
  const float* x     = (const float*)d_in[0];
  const float* Wxw   = (const float*)d_in[1];
  const float* Wxb   = (const float*)d_in[2];
  const float* resa  = (const float*)d_in[4];
  const float* Bw    = (const float*)d_in[6];
  const float* Uw    = (const float*)d_in[7];
  const float* Ub    = (const float*)d_in[8];
  const float* fg    = (const float*)d_in[9];
  const float* fb    = (const float*)d_in[10];
  const float* fftpw = (const float*)d_in[11];
  const float* fftpb = (const float*)d_in[12];
  const float* fmix  = (const float*)d_in[13];
  const float* mixl  = (const float*)d_in[14];
  const float* keyw  = (const float*)d_in[15];
  const float* keyb  = (const float*)d_in[16];
  const float* rmw   = (const float*)d_in[19];
  const float* rmb   = (const float*)d_in[20];
  const float* rng   = (const float*)d_in[21];
  const float* rnb   = (const float*)d_in[22];
  const float* mkeys = (const float*)d_in[23];
  const float* mvals = (const float*)d_in[24];
  const float* hebH  = (const float*)d_in[25];

  float* outp = (float*)d_out;
  float* hs   = outp;                               // (B,T,512)
  float* rout = outp + (size_t)65536 * 512;         // (B,T,512)

  unsigned short* wsu = (unsigned short*)d_ws;
  unsigned short* wxp    = wsu;                     // 131072
  unsigned short* keyp   = wsu + 131072;            // 98304
  unsigned short* bwp    = wsu + 229376;            // 262144
  unsigned short* uwp    = wsu + 491520;            // 131072
  unsigned short* fftps  = wsu + 622592;            // 262144
  float* wsf     = (float*)d_ws;
  float* partial = wsf + 524288;                    // 256*128
  float* q_ws    = wsf + 589824;                    // 1024
  float* hm      = wsf + 590848;                    // 4096
  float* cvec    = wsf + 594944;                    // 512

  k_wconv<<<3456, 256, 0, stream>>>(Wxw, keyw, Bw, Uw, fftpw, fg,
                                    wxp, keyp, bwp, uwp, fftps);
  k_cvec <<<2,    256, 0, stream>>>(fb, fftpw, cvec);
  k_rseq <<<1024, 512, 0, stream>>>(x, wxp, Wxb, resa, rng, rnb, rout);
  k_kq   <<<256,  512, 0, stream>>>(rout, x, keyp, keyb, partial);
  k_qred <<<4,    256, 0, stream>>>(partial, q_ws);
  k_mem  <<<8,    256, 0, stream>>>(q_ws, mkeys, mvals, hebH, rmw, rmb, mixl, hm);
  k_fused<<<1024, 512, 0, stream>>>(rout, x, bwp, uwp, Ub, fftps, fftpb,
                                    fmix, cvec, hm, hs);
}

// Round 6
// 396.777 us; speedup vs baseline: 2.7348x; 1.0362x over previous
//
#include <hip/hip_runtime.h>
#include <cmath>

// CRSDCell bf16-MFMA pipeline, round 6:
//  - k_fused LDS 78->40KB (half-staged sH + red overlays sA) -> 2+ blocks/CU.
//  - k_kq ported to lgkm-barrier reg-B template, BM=128, 512 blocks.
//  - Weights pre-packed chunk-major P[k0][slot4][n][8]; B-frags global->VGPR
//    one step ahead (L2-resident). Acts global->reg (s+2) / ds_write (s+1),
//    barriers are s_waitcnt lgkmcnt(0)+s_barrier: global loads stay in flight.
// FFT folds exactly: irfft(rfft(h)*s) = s*h. h_prev=r_prev=0 kills Wh/A terms.

typedef __attribute__((ext_vector_type(8)))  short short8;
typedef __attribute__((ext_vector_type(16))) float f32x16;

__device__ __forceinline__ unsigned short f2bf(float f) {
  union { float f; unsigned u; } v; v.f = f;
  unsigned r = v.u + 0x7FFF + ((v.u >> 16) & 1);   // RTNE
  return (unsigned short)(r >> 16);
}
__device__ __forceinline__ float bf2f(unsigned short h) {
  union { unsigned u; float f; } v; v.u = ((unsigned)h) << 16; return v.f;
}
__device__ __forceinline__ f32x16 mfma16(short8 a, short8 b, f32x16 c) {
  return __builtin_amdgcn_mfma_f32_32x32x16_bf16(a, b, c, 0, 0, 0);
}
__device__ __forceinline__ void barrier_lgkm() {
  asm volatile("s_waitcnt lgkmcnt(0)" ::: "memory");
  __builtin_amdgcn_s_barrier();
  __builtin_amdgcn_sched_barrier(0);
}

// ---------------- weight convert + pack ----------------
// packed offset for (n,k) in [N][K]: (k>>5)*N*32 + ((k>>3)&3)*N*8 + n*8 + (k&7)
__global__ __launch_bounds__(256) void k_wconv(
    const float* __restrict__ wx, const float* __restrict__ key,
    const float* __restrict__ bw, const float* __restrict__ uw,
    const float* __restrict__ fftpw, const float* __restrict__ fg,
    unsigned short* __restrict__ wxp, unsigned short* __restrict__ keyp,
    unsigned short* __restrict__ bwp, unsigned short* __restrict__ uwp,
    unsigned short* __restrict__ fftps) {
  int i = blockIdx.x * 256 + threadIdx.x;
  if (i >= 884736) return;
  float v; int n, k, N; unsigned short* dst;
  if (i < 131072)      { int j = i;          N = 512; k = j & 255; n = j >> 8; v = wx[j];  dst = wxp; }
  else if (i < 229376) { int j = i - 131072; N = 128; k = j % 768; n = j / 768; v = key[j]; dst = keyp; }
  else if (i < 491520) { int j = i - 229376; N = 512; k = j & 511; n = j >> 9; v = bw[j];  dst = bwp; }
  else if (i < 622592) { int j = i - 491520; N = 512; k = j & 255; n = j >> 8; v = uw[j];  dst = uwp; }
  else                 { int j = i - 622592; N = 512; k = j & 511; n = j >> 9; v = fftpw[j] * fg[k]; dst = fftps; }
  dst[(k >> 5) * (N * 32) + ((k >> 3) & 3) * (N * 8) + n * 8 + (k & 7)] = f2bf(v);
}

// ---------------- K1: r_seq (MFMA, BM=64, N=512, K=256, 8 n-waves) ----------
__global__ __launch_bounds__(512, 2) void k_rseq(
    const float* __restrict__ x, const unsigned short* __restrict__ wxp,
    const float* __restrict__ wxb, const float* __restrict__ resa,
    const float* __restrict__ rng, const float* __restrict__ rnb,
    float* __restrict__ rout) {
  __shared__ short sA[2][2048];    // [slot4][64][8]
  __shared__ float red[1152];
  const int t = threadIdx.x, w = t >> 6, lane = t & 63, lr = lane & 31, lh = lane >> 5;
  const int m0 = blockIdx.x * 64;

  f32x16 acc[2][2];
#pragma unroll
  for (int mi = 0; mi < 2; ++mi)
#pragma unroll
    for (int ni = 0; ni < 2; ++ni)
#pragma unroll
      for (int e = 0; e < 16; ++e) acc[mi][ni][e] = 0.f;

  short8 b0[4], b1[4];
  float4 a0, a1;

  auto loadB = [&](int sn, short8 (&bd)[4]) {
#pragma unroll
    for (int kh = 0; kh < 2; ++kh)
#pragma unroll
      for (int ni = 0; ni < 2; ++ni)
        bd[kh * 2 + ni] = *reinterpret_cast<const short8*>(
            wxp + (size_t)sn * 16384 + (kh * 2 + lh) * 4096 + (64 * w + 32 * ni + lr) * 8);
  };
  auto loadAct = [&](int sn, float4& ad) {
    int row = t >> 3, kq = t & 7;
    ad = *reinterpret_cast<const float4*>(x + (size_t)(m0 + row) * 256 + sn * 32 + kq * 4);
  };
  auto writeAct = [&](const float4& ad, int buf) {
    int row = t >> 3, kq = t & 7;
    uint2 p;
    p.x = (unsigned)f2bf(ad.x) | ((unsigned)f2bf(ad.y) << 16);
    p.y = (unsigned)f2bf(ad.z) | ((unsigned)f2bf(ad.w) << 16);
    *reinterpret_cast<uint2*>(&sA[buf][(kq >> 1) * 512 + row * 8 + (kq & 1) * 4]) = p;
  };
  auto mfstep = [&](int buf, short8 (&bc)[4]) {
    short8 af[4];
#pragma unroll
    for (int kh = 0; kh < 2; ++kh)
#pragma unroll
      for (int mi = 0; mi < 2; ++mi)
        af[kh * 2 + mi] = *reinterpret_cast<const short8*>(
            &sA[buf][(kh * 2 + lh) * 512 + (32 * mi + lr) * 8]);
    __builtin_amdgcn_s_setprio(1);
#pragma unroll
    for (int kh = 0; kh < 2; ++kh)
#pragma unroll
      for (int mi = 0; mi < 2; ++mi)
#pragma unroll
        for (int ni = 0; ni < 2; ++ni)
          acc[mi][ni] = mfma16(af[kh * 2 + mi], bc[kh * 2 + ni], acc[mi][ni]);
    __builtin_amdgcn_s_setprio(0);
  };

  const int NS = 8;
  loadAct(0, a0);
  loadB(0, b0);
  loadAct(1, a1);
  writeAct(a0, 0);
  barrier_lgkm();
  for (int s = 0; s < NS; s += 2) {
    if (s + 1 < NS) loadB(s + 1, b1);
    if (s + 2 < NS) loadAct(s + 2, a0);
    mfstep(s & 1, b0);
    if (s + 1 < NS) writeAct(a1, (s + 1) & 1);
    barrier_lgkm();
    if (s + 2 < NS) loadB(s + 2, b0);
    if (s + 3 < NS) loadAct(s + 3, a1);
    mfstep((s + 1) & 1, b1);
    if (s + 2 < NS) writeAct(a0, s & 1);
    barrier_lgkm();
  }

  // epilogue: z = (1-alpha)*tanh(acc+b), LN over 512 cols
#pragma unroll
  for (int ni = 0; ni < 2; ++ni) {
    int col = 64 * w + 32 * ni + lr;
    float al = 1.f / (1.f + expf(-resa[col >> 7]));
    float oma = 1.f - al, bbv = wxb[col];
#pragma unroll
    for (int mi = 0; mi < 2; ++mi)
#pragma unroll
      for (int r = 0; r < 16; ++r)
        acc[mi][ni][r] = oma * tanhf(acc[mi][ni][r] + bbv);
  }
#pragma unroll
  for (int mi = 0; mi < 2; ++mi)
#pragma unroll
    for (int r = 0; r < 16; ++r) {
      float s1 = acc[mi][0][r] + acc[mi][1][r];
      float s2 = acc[mi][0][r] * acc[mi][0][r] + acc[mi][1][r] * acc[mi][1][r];
#pragma unroll
      for (int m = 1; m <= 16; m <<= 1) { s1 += __shfl_xor(s1, m); s2 += __shfl_xor(s2, m); }
      int rl = (r & 3) + 8 * (r >> 2) + 4 * lh;
      if (lr == r) { red[(w * 2 + mi) * 32 + rl] = s1; red[512 + (w * 2 + mi) * 32 + rl] = s2; }
    }
  __syncthreads();
  if (t < 64) {
    int mi = t >> 5, rl = t & 31;
    float s1 = 0.f, s2 = 0.f;
#pragma unroll
    for (int n = 0; n < 8; ++n) { s1 += red[(n * 2 + mi) * 32 + rl]; s2 += red[512 + (n * 2 + mi) * 32 + rl]; }
    float mean = s1 * (1.f / 512.f);
    float var = s2 * (1.f / 512.f) - mean * mean;
    float rstd = rsqrtf(var + 1e-5f);
    red[1024 + t * 2] = mean;
    red[1024 + t * 2 + 1] = rstd;
  }
  __syncthreads();
#pragma unroll
  for (int q = 0; q < 4; ++q)
#pragma unroll
    for (int mi = 0; mi < 2; ++mi) {
      float4 stA = *reinterpret_cast<float4*>(&red[1024 + (32 * mi + 8 * q + 4 * lh) * 2]);
      float4 stB = *reinterpret_cast<float4*>(&red[1024 + (32 * mi + 8 * q + 4 * lh) * 2 + 4]);
      float mean[4] = {stA.x, stA.z, stB.x, stB.z};
      float rstd[4] = {stA.y, stA.w, stB.y, stB.w};
#pragma unroll
      for (int ni = 0; ni < 2; ++ni) {
        int col = 64 * w + 32 * ni + lr;
        float g = rng[col], bbv = rnb[col];
#pragma unroll
        for (int e = 0; e < 4; ++e) {
          int r = 4 * q + e;
          int grow = m0 + 32 * mi + 8 * q + 4 * lh + e;
          rout[(size_t)grow * 512 + col] = (acc[mi][ni][r] - mean[e]) * rstd[e] * g + bbv;
        }
      }
    }
}

// ---------------- K2: k + q partials (MFMA, BM=128, N=128, K=768) ----------
// 8 waves = 4m x 2n; each wave 32 rows x 64 cols, acc[2] (ni)
__global__ __launch_bounds__(512, 2) void k_kq(
    const float* __restrict__ rseq, const float* __restrict__ x,
    const unsigned short* __restrict__ keyp, const float* __restrict__ keyb,
    float* __restrict__ partial) {
  __shared__ short sA[2][4096];    // [slot4][128][8] (8KB each); red overlays after GEMM
  const int t = threadIdx.x, w = t >> 6, lane = t & 63, lr = lane & 31, lh = lane >> 5;
  const int mw = w >> 1, nw = w & 1;
  const int m0 = blockIdx.x * 128;

  f32x16 acc[2];
#pragma unroll
  for (int ni = 0; ni < 2; ++ni)
#pragma unroll
    for (int e = 0; e < 16; ++e) acc[ni][e] = 0.f;

  short8 b0[4], b1[4];
  float4 a0[2], a1[2];

  auto loadB = [&](int sn, short8 (&bd)[4]) {
#pragma unroll
    for (int kh = 0; kh < 2; ++kh)
#pragma unroll
      for (int ni = 0; ni < 2; ++ni)
        bd[kh * 2 + ni] = *reinterpret_cast<const short8*>(
            keyp + (size_t)sn * 4096 + (kh * 2 + lh) * 1024 + (64 * nw + 32 * ni + lr) * 8);
  };
  auto loadAct = [&](int sn, float4 (&ad)[2]) {
    const float* src; int str, kb;
    if (sn < 16) { src = rseq; str = 512; kb = sn * 32; }
    else         { src = x;    str = 256; kb = (sn - 16) * 32; }
#pragma unroll
    for (int i = 0; i < 2; ++i) {
      int c = t + i * 512, row = c >> 3, kq = c & 7;
      ad[i] = *reinterpret_cast<const float4*>(src + (size_t)(m0 + row) * str + kb + kq * 4);
    }
  };
  auto writeAct = [&](const float4 (&ad)[2], int buf) {
#pragma unroll
    for (int i = 0; i < 2; ++i) {
      int c = t + i * 512, row = c >> 3, kq = c & 7;
      uint2 p;
      p.x = (unsigned)f2bf(ad[i].x) | ((unsigned)f2bf(ad[i].y) << 16);
      p.y = (unsigned)f2bf(ad[i].z) | ((unsigned)f2bf(ad[i].w) << 16);
      *reinterpret_cast<uint2*>(&sA[buf][(kq >> 1) * 1024 + row * 8 + (kq & 1) * 4]) = p;
    }
  };
  auto mfstep = [&](int buf, short8 (&bc)[4]) {
    short8 af[2];
#pragma unroll
    for (int kh = 0; kh < 2; ++kh)
      af[kh] = *reinterpret_cast<const short8*>(
          &sA[buf][(kh * 2 + lh) * 1024 + (32 * mw + lr) * 8]);
    __builtin_amdgcn_s_setprio(1);
#pragma unroll
    for (int kh = 0; kh < 2; ++kh)
#pragma unroll
      for (int ni = 0; ni < 2; ++ni)
        acc[ni] = mfma16(af[kh], bc[kh * 2 + ni], acc[ni]);
    __builtin_amdgcn_s_setprio(0);
  };

  const int NS = 24;
  loadAct(0, a0);
  loadB(0, b0);
  loadAct(1, a1);
  writeAct(a0, 0);
  barrier_lgkm();
  for (int s = 0; s < NS; s += 2) {
    if (s + 1 < NS) loadB(s + 1, b1);
    if (s + 2 < NS) loadAct(s + 2, a0);
    mfstep(s & 1, b0);
    if (s + 1 < NS) writeAct(a1, (s + 1) & 1);
    barrier_lgkm();
    if (s + 2 < NS) loadB(s + 2, b0);
    if (s + 3 < NS) loadAct(s + 3, a1);
    mfstep((s + 1) & 1, b1);
    if (s + 2 < NS) writeAct(a0, s & 1);
    barrier_lgkm();
  }

  // + bias; per-row l2 scale; column partials of l2norm(k)
#pragma unroll
  for (int ni = 0; ni < 2; ++ni) {
    int col = 64 * nw + 32 * ni + lr;
    float bbv = keyb[col];
#pragma unroll
    for (int r = 0; r < 16; ++r) acc[ni][r] += bbv;
  }
  float* red = reinterpret_cast<float*>(sA);   // s2 @0[256], scale @256[128], qp @384[512]
#pragma unroll
  for (int r = 0; r < 16; ++r) {
    float s2 = acc[0][r] * acc[0][r] + acc[1][r] * acc[1][r];
#pragma unroll
    for (int m = 1; m <= 16; m <<= 1) s2 += __shfl_xor(s2, m);
    int rl = (r & 3) + 8 * (r >> 2) + 4 * lh;
    if (lr == r) red[(nw * 4 + mw) * 32 + rl] = s2;
  }
  __syncthreads();
  if (t < 128) {
    int ms = t >> 5, rl = t & 31;
    float s = red[(0 * 4 + ms) * 32 + rl] + red[(4 + ms) * 32 + rl];
    red[256 + ms * 32 + rl] = 1.f / fmaxf(sqrtf(s), 1e-8f);
  }
  __syncthreads();
  float p0 = 0.f, p1 = 0.f;
#pragma unroll
  for (int q = 0; q < 4; ++q) {
    float4 sc4 = *reinterpret_cast<float4*>(&red[256 + mw * 32 + 8 * q + 4 * lh]);
    float sc[4] = {sc4.x, sc4.y, sc4.z, sc4.w};
#pragma unroll
    for (int e = 0; e < 4; ++e) {
      int r = 4 * q + e;
      p0 += acc[0][r] * sc[e];
      p1 += acc[1][r] * sc[e];
    }
  }
  p0 += __shfl_xor(p0, 32);
  p1 += __shfl_xor(p1, 32);
  if (lh == 0) {
    red[384 + mw * 128 + 64 * nw + lr]      = p0;
    red[384 + mw * 128 + 64 * nw + 32 + lr] = p1;
  }
  __syncthreads();
  if (t < 128)
    partial[(size_t)blockIdx.x * 128 + t] =
        red[384 + t] + red[384 + 128 + t] + red[384 + 256 + t] + red[384 + 384 + t];
}

// ---------------- q reduce (512 blocks of 128 rows each) ----------------
__global__ __launch_bounds__(256) void k_qred(const float* __restrict__ partial,
                                              float* __restrict__ q_ws) {
  int gid = blockIdx.x * 256 + threadIdx.x;   // 0..1023
  int b = gid >> 7, c = gid & 127;
  float s = 0.f;
  for (int i = 0; i < 64; ++i) s += partial[(size_t)(b * 64 + i) * 128 + c];
  q_ws[gid] = s * (1.f / 8192.f);
}

// ---------------- cvec = fftn_b @ fftp_w^T (raw fftp) ----------------
__global__ __launch_bounds__(256) void k_cvec(const float* __restrict__ fb,
                                              const float* __restrict__ fftpw,
                                              float* __restrict__ cvec) {
  int o = blockIdx.x * 256 + threadIdx.x;     // 0..511
  const float* w = fftpw + (size_t)o * 512;
  float s = 0.f;
  for (int k = 0; k < 512; ++k) s += fb[k] * w[k];
  cvec[o] = s;
}

// ---------------- memory (episodic + hebbian) ----------------
__global__ __launch_bounds__(256) void k_mem(
    const float* __restrict__ q_ws, const float* __restrict__ mkeys,
    const float* __restrict__ mvals, const float* __restrict__ hebH,
    const float* __restrict__ rmw, const float* __restrict__ rmb,
    const float* __restrict__ mixl, float* __restrict__ hm) {
  const int b = blockIdx.x, t = threadIdx.x;
  __shared__ float qv[128];
  __shared__ float ssim[256];
  __shared__ float red[256];
  __shared__ float tval[8];
  __shared__ int tidx[8];
  __shared__ float wsm[8];
  __shared__ float vcs[128];

  if (t < 128) qv[t] = q_ws[b * 128 + t];
  __syncthreads();
  red[t] = (t < 128) ? qv[t] * qv[t] : 0.f;
  __syncthreads();
  for (int s = 128; s > 0; s >>= 1) {
    if (t < s) red[t] += red[t + s];
    __syncthreads();
  }
  float qsc = 1.f / fmaxf(sqrtf(red[0]), 1e-8f);
  {
    const float* mk = mkeys + ((size_t)b * 256 + t) * 128;
    float dot = 0.f, ms = 0.f;
    for (int k = 0; k < 128; ++k) { float mv = mk[k]; dot += qv[k] * mv; ms += mv * mv; }
    ssim[t] = dot * qsc / fmaxf(sqrtf(ms), 1e-8f);
  }
  __syncthreads();
  for (int it = 0; it < 8; ++it) {
    if (t < 64) {
      float bv = -1e30f; int bi = 0;
#pragma unroll
      for (int u = 0; u < 4; ++u) {
        int m = t * 4 + u;
        float v = ssim[m];
        if (v > bv) { bv = v; bi = m; }
      }
      for (int off = 32; off; off >>= 1) {
        float ov = __shfl_xor(bv, off, 64);
        int oi = __shfl_xor(bi, off, 64);
        if (ov > bv || (ov == bv && oi < bi)) { bv = ov; bi = oi; }
      }
      if (t == 0) { tval[it] = bv; tidx[it] = bi; ssim[bi] = -1e30f; }
    }
    __syncthreads();
  }
  if (t == 0) {
    float m0 = tval[0], sum = 0.f, e[8];
#pragma unroll
    for (int i = 0; i < 8; ++i) { e[i] = expf(tval[i] - m0); sum += e[i]; }
#pragma unroll
    for (int i = 0; i < 8; ++i) wsm[i] = e[i] / sum;
  }
  __syncthreads();
  float mix = 1.f / (1.f + expf(-mixl[0]));
  if (t < 128) {
    float vh = 0.f;
#pragma unroll
    for (int i = 0; i < 8; ++i) vh += wsm[i] * mvals[((size_t)b * 256 + tidx[i]) * 128 + t];
    float vhb = 0.f;
    const float* H = hebH + (size_t)b * 128 * 128;
    for (int k = 0; k < 128; ++k) vhb += qv[k] * H[k * 128 + t];
    vcs[t] = mix * vh + (1.f - mix) * vhb;
  }
  __syncthreads();
  for (int h = t; h < 512; h += 256) {
    float sum = rmb[h];
    const float* wr = rmw + (size_t)h * 128;
    for (int v = 0; v < 128; ++v) sum += vcs[v] * wr[v];
    hm[b * 512 + h] = sum;
  }
}

// ---------------- fused h_tilde -> LN -> fftp GEMM -> hs (BM=64) ------------
// LDS: sA 8KB (red overlays) + sH 32KB (half of h_norm) = 40KB
__global__ __launch_bounds__(512, 2) void k_fused(
    const float* __restrict__ rseq, const float* __restrict__ x,
    const unsigned short* __restrict__ bwp, const unsigned short* __restrict__ uwp,
    const float* __restrict__ ub, const unsigned short* __restrict__ fftps,
    const float* __restrict__ fftpb, const float* __restrict__ fmix,
    const float* __restrict__ cvec, const float* __restrict__ hm,
    float* __restrict__ hs) {
  __shared__ short sA[2][2048];    // [slot4][64][8]; red overlays after GEMM1
  __shared__ short sH[16384];      // [slot32][64][8] = half of h_norm (32KB)
  const int t = threadIdx.x, w = t >> 6, lane = t & 63, lr = lane & 31, lh = lane >> 5;
  const int m0 = blockIdx.x * 64;
  const int bidx = m0 >> 13;
  float* red = reinterpret_cast<float*>(sA);

  f32x16 acc[2][2];
#pragma unroll
  for (int mi = 0; mi < 2; ++mi)
#pragma unroll
    for (int ni = 0; ni < 2; ++ni)
#pragma unroll
      for (int e = 0; e < 16; ++e) acc[mi][ni][e] = 0.f;

  short8 b0[4], b1[4];
  float4 a0, a1;

  auto loadB1 = [&](int sn, short8 (&bd)[4]) {
    const unsigned short* wp = (sn < 16) ? (bwp + (size_t)sn * 16384)
                                         : (uwp + (size_t)(sn - 16) * 16384);
#pragma unroll
    for (int kh = 0; kh < 2; ++kh)
#pragma unroll
      for (int ni = 0; ni < 2; ++ni)
        bd[kh * 2 + ni] = *reinterpret_cast<const short8*>(
            wp + (kh * 2 + lh) * 4096 + (64 * w + 32 * ni + lr) * 8);
  };
  auto loadAct = [&](int sn, float4& ad) {
    const float* src; int str, kb;
    if (sn < 16) { src = rseq; str = 512; kb = sn * 32; }
    else         { src = x;    str = 256; kb = (sn - 16) * 32; }
    int row = t >> 3, kq = t & 7;
    ad = *reinterpret_cast<const float4*>(src + (size_t)(m0 + row) * str + kb + kq * 4);
  };
  auto writeAct = [&](const float4& ad, int buf) {
    int row = t >> 3, kq = t & 7;
    uint2 p;
    p.x = (unsigned)f2bf(ad.x) | ((unsigned)f2bf(ad.y) << 16);
    p.y = (unsigned)f2bf(ad.z) | ((unsigned)f2bf(ad.w) << 16);
    *reinterpret_cast<uint2*>(&sA[buf][(kq >> 1) * 512 + row * 8 + (kq & 1) * 4]) = p;
  };
  auto mfstep1 = [&](int buf, short8 (&bc)[4]) {
    short8 af[4];
#pragma unroll
    for (int kh = 0; kh < 2; ++kh)
#pragma unroll
      for (int mi = 0; mi < 2; ++mi)
        af[kh * 2 + mi] = *reinterpret_cast<const short8*>(
            &sA[buf][(kh * 2 + lh) * 512 + (32 * mi + lr) * 8]);
    __builtin_amdgcn_s_setprio(1);
#pragma unroll
    for (int kh = 0; kh < 2; ++kh)
#pragma unroll
      for (int mi = 0; mi < 2; ++mi)
#pragma unroll
        for (int ni = 0; ni < 2; ++ni)
          acc[mi][ni] = mfma16(af[kh * 2 + mi], bc[kh * 2 + ni], acc[mi][ni]);
    __builtin_amdgcn_s_setprio(0);
  };

  // ---- GEMM1: h_pre = [r,x] @ [Bw,Uw]^T, 24 K-steps ----
  const int NS = 24;
  loadAct(0, a0);
  loadB1(0, b0);
  loadAct(1, a1);
  writeAct(a0, 0);
  barrier_lgkm();
  for (int s = 0; s < NS; s += 2) {
    if (s + 1 < NS) loadB1(s + 1, b1);
    if (s + 2 < NS) loadAct(s + 2, a0);
    mfstep1(s & 1, b0);
    if (s + 1 < NS) writeAct(a1, (s + 1) & 1);
    barrier_lgkm();
    if (s + 2 < NS) loadB1(s + 2, b0);
    if (s + 3 < NS) loadAct(s + 3, a1);
    mfstep1((s + 1) & 1, b1);
    if (s + 2 < NS) writeAct(a0, s & 1);
    barrier_lgkm();
  }

  // ---- epilogue1: gelu, LN stats (red overlays sA), pack h~ ----
#pragma unroll
  for (int mi = 0; mi < 2; ++mi)
#pragma unroll
    for (int ni = 0; ni < 2; ++ni) {
      int col = 64 * w + 32 * ni + lr;
      float ubc = ub[col];
#pragma unroll
      for (int r = 0; r < 16; ++r) {
        float pre = acc[mi][ni][r] + ubc;
        acc[mi][ni][r] = 0.5f * pre * (1.f + erff(pre * 0.70710678118654752f));
      }
    }
#pragma unroll
  for (int mi = 0; mi < 2; ++mi)
#pragma unroll
    for (int r = 0; r < 16; ++r) {
      float s1 = acc[mi][0][r] + acc[mi][1][r];
      float s2 = acc[mi][0][r] * acc[mi][0][r] + acc[mi][1][r] * acc[mi][1][r];
#pragma unroll
      for (int m = 1; m <= 16; m <<= 1) { s1 += __shfl_xor(s1, m); s2 += __shfl_xor(s2, m); }
      int rl = (r & 3) + 8 * (r >> 2) + 4 * lh;
      if (lr == r) { red[(w * 2 + mi) * 32 + rl] = s1; red[512 + (w * 2 + mi) * 32 + rl] = s2; }
    }
  __syncthreads();
  if (t < 64) {
    int mi = t >> 5, rl = t & 31;
    float s1 = 0.f, s2 = 0.f;
#pragma unroll
    for (int n = 0; n < 8; ++n) { s1 += red[(n * 2 + mi) * 32 + rl]; s2 += red[512 + (n * 2 + mi) * 32 + rl]; }
    float mean = s1 * (1.f / 512.f);
    float var = s2 * (1.f / 512.f) - mean * mean;
    float rstd = rsqrtf(var + 1e-5f);
    red[1024 + t * 2] = mean;
    red[1024 + t * 2 + 1] = rstd;
  }
  __syncthreads();
  unsigned htp[2][2][8];
#pragma unroll
  for (int mi = 0; mi < 2; ++mi)
#pragma unroll
    for (int ni = 0; ni < 2; ++ni)
#pragma unroll
      for (int p = 0; p < 8; ++p)
        htp[mi][ni][p] = (unsigned)f2bf(acc[mi][ni][2 * p]) |
                         ((unsigned)f2bf(acc[mi][ni][2 * p + 1]) << 16);

  // write h_norm half (this wave's cols); half0 from acc (f32), half1 from htp
  auto writeZ = [&](bool fromAcc, int half) {
#pragma unroll
    for (int q = 0; q < 4; ++q)
#pragma unroll
      for (int mi = 0; mi < 2; ++mi) {
        float4 stA = *reinterpret_cast<float4*>(&red[1024 + (32 * mi + 8 * q + 4 * lh) * 2]);
        float4 stB = *reinterpret_cast<float4*>(&red[1024 + (32 * mi + 8 * q + 4 * lh) * 2 + 4]);
        float mean[4] = {stA.x, stA.z, stB.x, stB.z};
        float rstd[4] = {stA.y, stA.w, stB.y, stB.w};
#pragma unroll
        for (int ni = 0; ni < 2; ++ni) {
          int col = 64 * w + 32 * ni + lr;
#pragma unroll
          for (int e = 0; e < 4; ++e) {
            int r = 4 * q + e;
            float ht;
            if (fromAcc) ht = acc[mi][ni][r];
            else {
              unsigned pk = htp[mi][ni][r >> 1];
              ht = bf2f((unsigned short)((r & 1) ? (pk >> 16) : (pk & 0xFFFF)));
            }
            float z = (ht - mean[e]) * rstd[e];
            int rloc = 32 * mi + 8 * q + 4 * lh + e;
            sH[((col >> 3) - 32 * half) * 512 + rloc * 8 + (col & 7)] = (short)f2bf(z);
          }
        }
      }
  };
  if (w < 4) writeZ(true, 0);
#pragma unroll
  for (int mi = 0; mi < 2; ++mi)
#pragma unroll
    for (int ni = 0; ni < 2; ++ni)
#pragma unroll
      for (int e = 0; e < 16; ++e) acc[mi][ni][e] = 0.f;
  barrier_lgkm();

  // ---- GEMM2: h_norm @ (fftp*g)^T, two K-halves of 8 steps, barrier-free ----
  auto loadB2 = [&](int sn, short8 (&bd)[4]) {
#pragma unroll
    for (int kh = 0; kh < 2; ++kh)
#pragma unroll
      for (int ni = 0; ni < 2; ++ni)
        bd[kh * 2 + ni] = *reinterpret_cast<const short8*>(
            fftps + (size_t)sn * 16384 + (kh * 2 + lh) * 4096 + (64 * w + 32 * ni + lr) * 8);
  };
  auto mfstep2 = [&](int slotbase, short8 (&bc)[4]) {
    short8 af[4];
#pragma unroll
    for (int kh = 0; kh < 2; ++kh)
#pragma unroll
      for (int mi = 0; mi < 2; ++mi)
        af[kh * 2 + mi] = *reinterpret_cast<const short8*>(
            &sH[(slotbase + kh * 2 + lh) * 512 + (32 * mi + lr) * 8]);
    __builtin_amdgcn_s_setprio(1);
#pragma unroll
    for (int kh = 0; kh < 2; ++kh)
#pragma unroll
      for (int mi = 0; mi < 2; ++mi)
#pragma unroll
        for (int ni = 0; ni < 2; ++ni)
          acc[mi][ni] = mfma16(af[kh * 2 + mi], bc[kh * 2 + ni], acc[mi][ni]);
    __builtin_amdgcn_s_setprio(0);
  };
  loadB2(0, b0);
  for (int s = 0; s < 8; s += 2) {
    loadB2(s + 1, b1);
    mfstep2(s * 4, b0);
    loadB2(s + 2, b0);            // s+2==8 prefetches first step of half 1
    mfstep2((s + 1) * 4, b1);
  }
  barrier_lgkm();                 // all waves done reading half 0
  if (w >= 4) writeZ(false, 1);
  barrier_lgkm();                 // half 1 visible
  for (int s = 8; s < 16; s += 2) {
    loadB2(s + 1, b1);
    mfstep2((s - 8) * 4, b0);
    if (s + 2 < 16) loadB2(s + 2, b0);
    mfstep2((s - 7) * 4, b1);
  }

  // ---- epilogue2: combine ----
  const float sg = 1.f / (1.f + expf(-fmix[0]));
  const float s2f = sg * sg, oms = 1.f - sg;
#pragma unroll
  for (int mi = 0; mi < 2; ++mi)
#pragma unroll
    for (int ni = 0; ni < 2; ++ni) {
      int col = 64 * w + 32 * ni + lr;
      float base = s2f * cvec[col] + sg * fftpb[col] + 0.5f * hm[bidx * 512 + col];
#pragma unroll
      for (int p = 0; p < 8; ++p) {
        unsigned pk = htp[mi][ni][p];
        int r0 = 2 * p;
        int rloc = 32 * mi + (r0 & 3) + 8 * (r0 >> 2) + 4 * lh;
        float o0 = oms * bf2f((unsigned short)(pk & 0xFFFF)) + s2f * acc[mi][ni][r0] + base;
        float o1 = oms * bf2f((unsigned short)(pk >> 16)) + s2f * acc[mi][ni][r0 + 1] + base;
        hs[(size_t)(m0 + rloc) * 512 + col] = o0;
        hs[(size_t)(m0 + rloc + 1) * 512 + col] = o1;
      }
    }
}

extern "C" void kernel_launch(void* const* d_in, const int* in_sizes, int n_in,
                              void* d_out, int out_size, void* d_ws, size_t ws_size,
                              hipStream_t stream) {
  (void)in_sizes; (void)n_in; (void)out_size; (void)ws_size;
  const float* x     = (const float*)d_in[0];
  const float* Wxw   = (const float*)d_in[1];
  const float* Wxb   = (const float*)d_in[2];
  const float* resa  = (const float*)d_in[4];
  const float* Bw    = (const float*)d_in[6];
  const float* Uw    = (const float*)d_in[7];
  const float* Ub    = (const float*)d_in[8];
  const float* fg    = (const float*)d_in[9];
  const float* fb    = (const float*)d_in[10];
  const float* fftpw = (const float*)d_in[11];
  const float* fftpb = (const float*)d_in[12];
  const float* fmix  = (const float*)d_in[13];
  const float* mixl  = (const float*)d_in[14];
  const float* keyw  = (const float*)d_in[15];
  const float* keyb  = (const float*)d_in[16];
  const float* rmw   = (const float*)d_in[19];
  const float* rmb   = (const float*)d_in[20];
  const float* rng   = (const float*)d_in[21];
  const float* rnb   = (const float*)d_in[22];
  const float* mkeys = (const float*)d_in[23];
  const float* mvals = (const float*)d_in[24];
  const float* hebH  = (const float*)d_in[25];

  float* outp = (float*)d_out;
  float* hs   = outp;                               // (B,T,512)
  float* rout = outp + (size_t)65536 * 512;         // (B,T,512)

  unsigned short* wsu = (unsigned short*)d_ws;
  unsigned short* wxp    = wsu;                     // 131072
  unsigned short* keyp   = wsu + 131072;            // 98304
  unsigned short* bwp    = wsu + 229376;            // 262144
  unsigned short* uwp    = wsu + 491520;            // 131072
  unsigned short* fftps  = wsu + 622592;            // 262144
  float* wsf     = (float*)d_ws;
  float* partial = wsf + 524288;                    // 512*128
  float* q_ws    = wsf + 589824;                    // 1024
  float* hm      = wsf + 590848;                    // 4096
  float* cvec    = wsf + 594944;                    // 512

  k_wconv<<<3456, 256, 0, stream>>>(Wxw, keyw, Bw, Uw, fftpw, fg,
                                    wxp, keyp, bwp, uwp, fftps);
  k_cvec <<<2,    256, 0, stream>>>(fb, fftpw, cvec);
  k_rseq <<<1024, 512, 0, stream>>>(x, wxp, Wxb, resa, rng, rnb, rout);
  k_kq   <<<512,  512, 0, stream>>>(rout, x, keyp, keyb, partial);
  k_qred <<<4,    256, 0, stream>>>(partial, q_ws);
  k_mem  <<<8,    256, 0, stream>>>(q_ws, mkeys, mvals, hebH, rmw, rmb, mixl, hm);
  k_fused<<<1024, 512, 0, stream>>>(rout, x, bwp, uwp, Ub, fftps, fftpb,
                                    fmix, cvec, hm, hs);
}

// Round 7
// 311.682 us; speedup vs baseline: 3.4814x; 1.2730x over previous
//
#include <hip/hip_runtime.h>
#include <cmath>

// CRSDCell bf16-MFMA pipeline, round 7: BM=32 + launch_bounds(512,4) to fit
// the unified VGPR+AGPR budget (<=128/wave) -> 2 blocks/CU.
//  - Wave decomp 1m x 8n: each wave 32 rows x 64 cols, acc[2] = 32 regs.
//  - Weights pre-packed chunk-major P[k0][slot4][n][8]; B-frags global->VGPR
//    one step ahead (L2-resident). Acts global->reg (s+2) / ds_write (s+1).
//  - Barriers are s_waitcnt lgkmcnt(0)+s_barrier: global loads stay in flight.
//  - k_fused: sH = full 32x512 h_norm (32KB), GEMM2 fully barrier-free.
// FFT folds exactly: irfft(rfft(h)*s) = s*h. h_prev=r_prev=0 kills Wh/A terms.

typedef __attribute__((ext_vector_type(8)))  short short8;
typedef __attribute__((ext_vector_type(16))) float f32x16;

__device__ __forceinline__ unsigned short f2bf(float f) {
  union { float f; unsigned u; } v; v.f = f;
  unsigned r = v.u + 0x7FFF + ((v.u >> 16) & 1);   // RTNE
  return (unsigned short)(r >> 16);
}
__device__ __forceinline__ float bf2f(unsigned short h) {
  union { unsigned u; float f; } v; v.u = ((unsigned)h) << 16; return v.f;
}
__device__ __forceinline__ f32x16 mfma16(short8 a, short8 b, f32x16 c) {
  return __builtin_amdgcn_mfma_f32_32x32x16_bf16(a, b, c, 0, 0, 0);
}
// copy 1KB: 64 lanes x 16B, contiguous global -> linear LDS (k_kq only)
__device__ __forceinline__ void glds1k(const unsigned short* g, short* l, int lane) {
  typedef const __attribute__((address_space(1))) unsigned int* gp_t;
  typedef __attribute__((address_space(3))) unsigned int* lp_t;
  __builtin_amdgcn_global_load_lds((gp_t)(const void*)(g + lane * 8),
                                   (lp_t)(void*)l, 16, 0, 0);
}
__device__ __forceinline__ void barrier_lgkm() {
  asm volatile("s_waitcnt lgkmcnt(0)" ::: "memory");
  __builtin_amdgcn_s_barrier();
  __builtin_amdgcn_sched_barrier(0);
}

// ---------------- weight convert + pack ----------------
// packed offset for (n,k) in [N][K]: (k>>5)*N*32 + ((k>>3)&3)*N*8 + n*8 + (k&7)
__global__ __launch_bounds__(256) void k_wconv(
    const float* __restrict__ wx, const float* __restrict__ key,
    const float* __restrict__ bw, const float* __restrict__ uw,
    const float* __restrict__ fftpw, const float* __restrict__ fg,
    unsigned short* __restrict__ wxp, unsigned short* __restrict__ keyp,
    unsigned short* __restrict__ bwp, unsigned short* __restrict__ uwp,
    unsigned short* __restrict__ fftps) {
  int i = blockIdx.x * 256 + threadIdx.x;
  if (i >= 884736) return;
  float v; int n, k, N; unsigned short* dst;
  if (i < 131072)      { int j = i;          N = 512; k = j & 255; n = j >> 8; v = wx[j];  dst = wxp; }
  else if (i < 229376) { int j = i - 131072; N = 128; k = j % 768; n = j / 768; v = key[j]; dst = keyp; }
  else if (i < 491520) { int j = i - 229376; N = 512; k = j & 511; n = j >> 9; v = bw[j];  dst = bwp; }
  else if (i < 622592) { int j = i - 491520; N = 512; k = j & 255; n = j >> 8; v = uw[j];  dst = uwp; }
  else                 { int j = i - 622592; N = 512; k = j & 511; n = j >> 9; v = fftpw[j] * fg[k]; dst = fftps; }
  dst[(k >> 5) * (N * 32) + ((k >> 3) & 3) * (N * 8) + n * 8 + (k & 7)] = f2bf(v);
}

// ---------------- K1: r_seq (MFMA, BM=32, N=512, K=256, 8 n-waves) ----------
__global__ __launch_bounds__(512, 4) void k_rseq(
    const float* __restrict__ x, const unsigned short* __restrict__ wxp,
    const float* __restrict__ wxb, const float* __restrict__ resa,
    const float* __restrict__ rng, const float* __restrict__ rnb,
    float* __restrict__ rout) {
  __shared__ short sA[2][1024];    // [slot4][32][8]
  __shared__ float red[640];
  const int t = threadIdx.x, w = t >> 6, lane = t & 63, lr = lane & 31, lh = lane >> 5;
  const int m0 = blockIdx.x * 32;

  f32x16 acc[2];
#pragma unroll
  for (int ni = 0; ni < 2; ++ni)
#pragma unroll
    for (int e = 0; e < 16; ++e) acc[ni][e] = 0.f;

  short8 b0[4], b1[4];
  float2 a0, a1;

  auto loadB = [&](int sn, short8 (&bd)[4]) {
#pragma unroll
    for (int kh = 0; kh < 2; ++kh)
#pragma unroll
      for (int ni = 0; ni < 2; ++ni)
        bd[kh * 2 + ni] = *reinterpret_cast<const short8*>(
            wxp + (size_t)sn * 16384 + (kh * 2 + lh) * 4096 + (64 * w + 32 * ni + lr) * 8);
  };
  auto loadAct = [&](int sn, float2& ad) {
    int row = t >> 4, kq2 = t & 15;
    ad = *reinterpret_cast<const float2*>(x + (size_t)(m0 + row) * 256 + sn * 32 + kq2 * 2);
  };
  auto writeAct = [&](const float2& ad, int buf) {
    int row = t >> 4, kq2 = t & 15;
    unsigned p = (unsigned)f2bf(ad.x) | ((unsigned)f2bf(ad.y) << 16);
    *reinterpret_cast<unsigned*>(&sA[buf][(kq2 >> 2) * 256 + row * 8 + (kq2 & 3) * 2]) = p;
  };
  auto mfstep = [&](int buf, short8 (&bc)[4]) {
    short8 af[2];
#pragma unroll
    for (int kh = 0; kh < 2; ++kh)
      af[kh] = *reinterpret_cast<const short8*>(&sA[buf][(kh * 2 + lh) * 256 + lr * 8]);
    __builtin_amdgcn_s_setprio(1);
#pragma unroll
    for (int kh = 0; kh < 2; ++kh)
#pragma unroll
      for (int ni = 0; ni < 2; ++ni)
        acc[ni] = mfma16(af[kh], bc[kh * 2 + ni], acc[ni]);
    __builtin_amdgcn_s_setprio(0);
  };

  const int NS = 8;
  loadAct(0, a0);
  loadB(0, b0);
  loadAct(1, a1);
  writeAct(a0, 0);
  barrier_lgkm();
  for (int s = 0; s < NS; s += 2) {
    if (s + 1 < NS) loadB(s + 1, b1);
    if (s + 2 < NS) loadAct(s + 2, a0);
    mfstep(s & 1, b0);
    if (s + 1 < NS) writeAct(a1, (s + 1) & 1);
    barrier_lgkm();
    if (s + 2 < NS) loadB(s + 2, b0);
    if (s + 3 < NS) loadAct(s + 3, a1);
    mfstep((s + 1) & 1, b1);
    if (s + 2 < NS) writeAct(a0, s & 1);
    barrier_lgkm();
  }

  // epilogue: z = (1-alpha)*tanh(acc+b), LN over 512 cols (rows 0..31)
#pragma unroll
  for (int ni = 0; ni < 2; ++ni) {
    int col = 64 * w + 32 * ni + lr;
    float al = 1.f / (1.f + expf(-resa[col >> 7]));
    float oma = 1.f - al, bbv = wxb[col];
#pragma unroll
    for (int r = 0; r < 16; ++r)
      acc[ni][r] = oma * tanhf(acc[ni][r] + bbv);
  }
#pragma unroll
  for (int r = 0; r < 16; ++r) {
    float s1 = acc[0][r] + acc[1][r];
    float s2 = acc[0][r] * acc[0][r] + acc[1][r] * acc[1][r];
#pragma unroll
    for (int m = 1; m <= 16; m <<= 1) { s1 += __shfl_xor(s1, m); s2 += __shfl_xor(s2, m); }
    int rl = (r & 3) + 8 * (r >> 2) + 4 * lh;
    if (lr == r) { red[w * 32 + rl] = s1; red[256 + w * 32 + rl] = s2; }
  }
  __syncthreads();
  if (t < 32) {
    float s1 = 0.f, s2 = 0.f;
#pragma unroll
    for (int n = 0; n < 8; ++n) { s1 += red[n * 32 + t]; s2 += red[256 + n * 32 + t]; }
    float mean = s1 * (1.f / 512.f);
    float var = s2 * (1.f / 512.f) - mean * mean;
    float rstd = rsqrtf(var + 1e-5f);
    red[512 + t * 2] = mean;
    red[512 + t * 2 + 1] = rstd;
  }
  __syncthreads();
#pragma unroll
  for (int q = 0; q < 4; ++q) {
    float4 stA = *reinterpret_cast<float4*>(&red[512 + (8 * q + 4 * lh) * 2]);
    float4 stB = *reinterpret_cast<float4*>(&red[512 + (8 * q + 4 * lh) * 2 + 4]);
    float mean[4] = {stA.x, stA.z, stB.x, stB.z};
    float rstd[4] = {stA.y, stA.w, stB.y, stB.w};
#pragma unroll
    for (int ni = 0; ni < 2; ++ni) {
      int col = 64 * w + 32 * ni + lr;
      float g = rng[col], bbv = rnb[col];
#pragma unroll
      for (int e = 0; e < 4; ++e) {
        int r = 4 * q + e;
        int grow = m0 + 8 * q + 4 * lh + e;
        rout[(size_t)grow * 512 + col] = (acc[ni][r] - mean[e]) * rstd[e] * g + bbv;
      }
    }
  }
}

// ---------------- K2: k + q partials (MFMA, BM=128, N=128, K=768) ----------
// 8 waves = 4m x 2n; each wave 32 rows x 64 cols, acc[2] (ni)
__global__ __launch_bounds__(512, 2) void k_kq(
    const float* __restrict__ rseq, const float* __restrict__ x,
    const unsigned short* __restrict__ keyp, const float* __restrict__ keyb,
    float* __restrict__ partial) {
  __shared__ short sA[2][4096];    // [slot4][128][8] (8KB each); red overlays after GEMM
  const int t = threadIdx.x, w = t >> 6, lane = t & 63, lr = lane & 31, lh = lane >> 5;
  const int mw = w >> 1, nw = w & 1;
  const int m0 = blockIdx.x * 128;

  f32x16 acc[2];
#pragma unroll
  for (int ni = 0; ni < 2; ++ni)
#pragma unroll
    for (int e = 0; e < 16; ++e) acc[ni][e] = 0.f;

  short8 b0[4], b1[4];
  float4 a0[2], a1[2];

  auto loadB = [&](int sn, short8 (&bd)[4]) {
#pragma unroll
    for (int kh = 0; kh < 2; ++kh)
#pragma unroll
      for (int ni = 0; ni < 2; ++ni)
        bd[kh * 2 + ni] = *reinterpret_cast<const short8*>(
            keyp + (size_t)sn * 4096 + (kh * 2 + lh) * 1024 + (64 * nw + 32 * ni + lr) * 8);
  };
  auto loadAct = [&](int sn, float4 (&ad)[2]) {
    const float* src; int str, kb;
    if (sn < 16) { src = rseq; str = 512; kb = sn * 32; }
    else         { src = x;    str = 256; kb = (sn - 16) * 32; }
#pragma unroll
    for (int i = 0; i < 2; ++i) {
      int c = t + i * 512, row = c >> 3, kq = c & 7;
      ad[i] = *reinterpret_cast<const float4*>(src + (size_t)(m0 + row) * str + kb + kq * 4);
    }
  };
  auto writeAct = [&](const float4 (&ad)[2], int buf) {
#pragma unroll
    for (int i = 0; i < 2; ++i) {
      int c = t + i * 512, row = c >> 3, kq = c & 7;
      uint2 p;
      p.x = (unsigned)f2bf(ad[i].x) | ((unsigned)f2bf(ad[i].y) << 16);
      p.y = (unsigned)f2bf(ad[i].z) | ((unsigned)f2bf(ad[i].w) << 16);
      *reinterpret_cast<uint2*>(&sA[buf][(kq >> 1) * 1024 + row * 8 + (kq & 1) * 4]) = p;
    }
  };
  auto mfstep = [&](int buf, short8 (&bc)[4]) {
    short8 af[2];
#pragma unroll
    for (int kh = 0; kh < 2; ++kh)
      af[kh] = *reinterpret_cast<const short8*>(
          &sA[buf][(kh * 2 + lh) * 1024 + (32 * mw + lr) * 8]);
    __builtin_amdgcn_s_setprio(1);
#pragma unroll
    for (int kh = 0; kh < 2; ++kh)
#pragma unroll
      for (int ni = 0; ni < 2; ++ni)
        acc[ni] = mfma16(af[kh], bc[kh * 2 + ni], acc[ni]);
    __builtin_amdgcn_s_setprio(0);
  };

  const int NS = 24;
  loadAct(0, a0);
  loadB(0, b0);
  loadAct(1, a1);
  writeAct(a0, 0);
  barrier_lgkm();
  for (int s = 0; s < NS; s += 2) {
    if (s + 1 < NS) loadB(s + 1, b1);
    if (s + 2 < NS) loadAct(s + 2, a0);
    mfstep(s & 1, b0);
    if (s + 1 < NS) writeAct(a1, (s + 1) & 1);
    barrier_lgkm();
    if (s + 2 < NS) loadB(s + 2, b0);
    if (s + 3 < NS) loadAct(s + 3, a1);
    mfstep((s + 1) & 1, b1);
    if (s + 2 < NS) writeAct(a0, s & 1);
    barrier_lgkm();
  }

  // + bias; per-row l2 scale; column partials of l2norm(k)
#pragma unroll
  for (int ni = 0; ni < 2; ++ni) {
    int col = 64 * nw + 32 * ni + lr;
    float bbv = keyb[col];
#pragma unroll
    for (int r = 0; r < 16; ++r) acc[ni][r] += bbv;
  }
  float* red = reinterpret_cast<float*>(sA);   // s2 @0[256], scale @256[128], qp @384[512]
#pragma unroll
  for (int r = 0; r < 16; ++r) {
    float s2 = acc[0][r] * acc[0][r] + acc[1][r] * acc[1][r];
#pragma unroll
    for (int m = 1; m <= 16; m <<= 1) s2 += __shfl_xor(s2, m);
    int rl = (r & 3) + 8 * (r >> 2) + 4 * lh;
    if (lr == r) red[(nw * 4 + mw) * 32 + rl] = s2;
  }
  __syncthreads();
  if (t < 128) {
    int ms = t >> 5, rl = t & 31;
    float s = red[(0 * 4 + ms) * 32 + rl] + red[(4 + ms) * 32 + rl];
    red[256 + ms * 32 + rl] = 1.f / fmaxf(sqrtf(s), 1e-8f);
  }
  __syncthreads();
  float p0 = 0.f, p1 = 0.f;
#pragma unroll
  for (int q = 0; q < 4; ++q) {
    float4 sc4 = *reinterpret_cast<float4*>(&red[256 + mw * 32 + 8 * q + 4 * lh]);
    float sc[4] = {sc4.x, sc4.y, sc4.z, sc4.w};
#pragma unroll
    for (int e = 0; e < 4; ++e) {
      int r = 4 * q + e;
      p0 += acc[0][r] * sc[e];
      p1 += acc[1][r] * sc[e];
    }
  }
  p0 += __shfl_xor(p0, 32);
  p1 += __shfl_xor(p1, 32);
  if (lh == 0) {
    red[384 + mw * 128 + 64 * nw + lr]      = p0;
    red[384 + mw * 128 + 64 * nw + 32 + lr] = p1;
  }
  __syncthreads();
  if (t < 128)
    partial[(size_t)blockIdx.x * 128 + t] =
        red[384 + t] + red[384 + 128 + t] + red[384 + 256 + t] + red[384 + 384 + t];
}

// ---------------- q reduce (512 blocks of 128 rows each) ----------------
__global__ __launch_bounds__(256) void k_qred(const float* __restrict__ partial,
                                              float* __restrict__ q_ws) {
  int gid = blockIdx.x * 256 + threadIdx.x;   // 0..1023
  int b = gid >> 7, c = gid & 127;
  float s = 0.f;
  for (int i = 0; i < 64; ++i) s += partial[(size_t)(b * 64 + i) * 128 + c];
  q_ws[gid] = s * (1.f / 8192.f);
}

// ---------------- cvec = fftn_b @ fftp_w^T (raw fftp) ----------------
__global__ __launch_bounds__(256) void k_cvec(const float* __restrict__ fb,
                                              const float* __restrict__ fftpw,
                                              float* __restrict__ cvec) {
  int o = blockIdx.x * 256 + threadIdx.x;     // 0..511
  const float* w = fftpw + (size_t)o * 512;
  float s = 0.f;
  for (int k = 0; k < 512; ++k) s += fb[k] * w[k];
  cvec[o] = s;
}

// ---------------- memory (episodic + hebbian) ----------------
__global__ __launch_bounds__(256) void k_mem(
    const float* __restrict__ q_ws, const float* __restrict__ mkeys,
    const float* __restrict__ mvals, const float* __restrict__ hebH,
    const float* __restrict__ rmw, const float* __restrict__ rmb,
    const float* __restrict__ mixl, float* __restrict__ hm) {
  const int b = blockIdx.x, t = threadIdx.x;
  __shared__ float qv[128];
  __shared__ float ssim[256];
  __shared__ float red[256];
  __shared__ float tval[8];
  __shared__ int tidx[8];
  __shared__ float wsm[8];
  __shared__ float vcs[128];

  if (t < 128) qv[t] = q_ws[b * 128 + t];
  __syncthreads();
  red[t] = (t < 128) ? qv[t] * qv[t] : 0.f;
  __syncthreads();
  for (int s = 128; s > 0; s >>= 1) {
    if (t < s) red[t] += red[t + s];
    __syncthreads();
  }
  float qsc = 1.f / fmaxf(sqrtf(red[0]), 1e-8f);
  {
    const float* mk = mkeys + ((size_t)b * 256 + t) * 128;
    float dot = 0.f, ms = 0.f;
    for (int k = 0; k < 128; ++k) { float mv = mk[k]; dot += qv[k] * mv; ms += mv * mv; }
    ssim[t] = dot * qsc / fmaxf(sqrtf(ms), 1e-8f);
  }
  __syncthreads();
  for (int it = 0; it < 8; ++it) {
    if (t < 64) {
      float bv = -1e30f; int bi = 0;
#pragma unroll
      for (int u = 0; u < 4; ++u) {
        int m = t * 4 + u;
        float v = ssim[m];
        if (v > bv) { bv = v; bi = m; }
      }
      for (int off = 32; off; off >>= 1) {
        float ov = __shfl_xor(bv, off, 64);
        int oi = __shfl_xor(bi, off, 64);
        if (ov > bv || (ov == bv && oi < bi)) { bv = ov; bi = oi; }
      }
      if (t == 0) { tval[it] = bv; tidx[it] = bi; ssim[bi] = -1e30f; }
    }
    __syncthreads();
  }
  if (t == 0) {
    float m0 = tval[0], sum = 0.f, e[8];
#pragma unroll
    for (int i = 0; i < 8; ++i) { e[i] = expf(tval[i] - m0); sum += e[i]; }
#pragma unroll
    for (int i = 0; i < 8; ++i) wsm[i] = e[i] / sum;
  }
  __syncthreads();
  float mix = 1.f / (1.f + expf(-mixl[0]));
  if (t < 128) {
    float vh = 0.f;
#pragma unroll
    for (int i = 0; i < 8; ++i) vh += wsm[i] * mvals[((size_t)b * 256 + tidx[i]) * 128 + t];
    float vhb = 0.f;
    const float* H = hebH + (size_t)b * 128 * 128;
    for (int k = 0; k < 128; ++k) vhb += qv[k] * H[k * 128 + t];
    vcs[t] = mix * vh + (1.f - mix) * vhb;
  }
  __syncthreads();
  for (int h = t; h < 512; h += 256) {
    float sum = rmb[h];
    const float* wr = rmw + (size_t)h * 128;
    for (int v = 0; v < 128; ++v) sum += vcs[v] * wr[v];
    hm[b * 512 + h] = sum;
  }
}

// ---------------- fused h_tilde -> LN -> fftp GEMM -> hs (BM=32) ------------
// LDS: sA 4KB + red 2.5KB + sH 32KB (full 32x512 h_norm)
__global__ __launch_bounds__(512, 4) void k_fused(
    const float* __restrict__ rseq, const float* __restrict__ x,
    const unsigned short* __restrict__ bwp, const unsigned short* __restrict__ uwp,
    const float* __restrict__ ub, const unsigned short* __restrict__ fftps,
    const float* __restrict__ fftpb, const float* __restrict__ fmix,
    const float* __restrict__ cvec, const float* __restrict__ hm,
    float* __restrict__ hs) {
  __shared__ short sA[2][1024];    // [slot4][32][8]
  __shared__ short sH[16384];      // [slot64][32][8] = full h_norm (32KB)
  __shared__ float red[640];
  const int t = threadIdx.x, w = t >> 6, lane = t & 63, lr = lane & 31, lh = lane >> 5;
  const int m0 = blockIdx.x * 32;
  const int bidx = m0 >> 13;

  f32x16 acc[2];
#pragma unroll
  for (int ni = 0; ni < 2; ++ni)
#pragma unroll
    for (int e = 0; e < 16; ++e) acc[ni][e] = 0.f;

  short8 b0[4], b1[4];
  float2 a0, a1;

  auto loadB1 = [&](int sn, short8 (&bd)[4]) {
    const unsigned short* wp = (sn < 16) ? (bwp + (size_t)sn * 16384)
                                         : (uwp + (size_t)(sn - 16) * 16384);
#pragma unroll
    for (int kh = 0; kh < 2; ++kh)
#pragma unroll
      for (int ni = 0; ni < 2; ++ni)
        bd[kh * 2 + ni] = *reinterpret_cast<const short8*>(
            wp + (kh * 2 + lh) * 4096 + (64 * w + 32 * ni + lr) * 8);
  };
  auto loadAct = [&](int sn, float2& ad) {
    const float* src; int str, kb;
    if (sn < 16) { src = rseq; str = 512; kb = sn * 32; }
    else         { src = x;    str = 256; kb = (sn - 16) * 32; }
    int row = t >> 4, kq2 = t & 15;
    ad = *reinterpret_cast<const float2*>(src + (size_t)(m0 + row) * str + kb + kq2 * 2);
  };
  auto writeAct = [&](const float2& ad, int buf) {
    int row = t >> 4, kq2 = t & 15;
    unsigned p = (unsigned)f2bf(ad.x) | ((unsigned)f2bf(ad.y) << 16);
    *reinterpret_cast<unsigned*>(&sA[buf][(kq2 >> 2) * 256 + row * 8 + (kq2 & 3) * 2]) = p;
  };
  auto mfstep1 = [&](int buf, short8 (&bc)[4]) {
    short8 af[2];
#pragma unroll
    for (int kh = 0; kh < 2; ++kh)
      af[kh] = *reinterpret_cast<const short8*>(&sA[buf][(kh * 2 + lh) * 256 + lr * 8]);
    __builtin_amdgcn_s_setprio(1);
#pragma unroll
    for (int kh = 0; kh < 2; ++kh)
#pragma unroll
      for (int ni = 0; ni < 2; ++ni)
        acc[ni] = mfma16(af[kh], bc[kh * 2 + ni], acc[ni]);
    __builtin_amdgcn_s_setprio(0);
  };

  // ---- GEMM1: h_pre = [r,x] @ [Bw,Uw]^T, 24 K-steps ----
  const int NS = 24;
  loadAct(0, a0);
  loadB1(0, b0);
  loadAct(1, a1);
  writeAct(a0, 0);
  barrier_lgkm();
  for (int s = 0; s < NS; s += 2) {
    if (s + 1 < NS) loadB1(s + 1, b1);
    if (s + 2 < NS) loadAct(s + 2, a0);
    mfstep1(s & 1, b0);
    if (s + 1 < NS) writeAct(a1, (s + 1) & 1);
    barrier_lgkm();
    if (s + 2 < NS) loadB1(s + 2, b0);
    if (s + 3 < NS) loadAct(s + 3, a1);
    mfstep1((s + 1) & 1, b1);
    if (s + 2 < NS) writeAct(a0, s & 1);
    barrier_lgkm();
  }

  // ---- epilogue1: gelu, LN stats, pack h~, write full sH ----
#pragma unroll
  for (int ni = 0; ni < 2; ++ni) {
    int col = 64 * w + 32 * ni + lr;
    float ubc = ub[col];
#pragma unroll
    for (int r = 0; r < 16; ++r) {
      float pre = acc[ni][r] + ubc;
      acc[ni][r] = 0.5f * pre * (1.f + erff(pre * 0.70710678118654752f));
    }
  }
#pragma unroll
  for (int r = 0; r < 16; ++r) {
    float s1 = acc[0][r] + acc[1][r];
    float s2 = acc[0][r] * acc[0][r] + acc[1][r] * acc[1][r];
#pragma unroll
    for (int m = 1; m <= 16; m <<= 1) { s1 += __shfl_xor(s1, m); s2 += __shfl_xor(s2, m); }
    int rl = (r & 3) + 8 * (r >> 2) + 4 * lh;
    if (lr == r) { red[w * 32 + rl] = s1; red[256 + w * 32 + rl] = s2; }
  }
  __syncthreads();
  if (t < 32) {
    float s1 = 0.f, s2 = 0.f;
#pragma unroll
    for (int n = 0; n < 8; ++n) { s1 += red[n * 32 + t]; s2 += red[256 + n * 32 + t]; }
    float mean = s1 * (1.f / 512.f);
    float var = s2 * (1.f / 512.f) - mean * mean;
    float rstd = rsqrtf(var + 1e-5f);
    red[512 + t * 2] = mean;
    red[512 + t * 2 + 1] = rstd;
  }
  __syncthreads();
  unsigned htp[2][8];
#pragma unroll
  for (int ni = 0; ni < 2; ++ni)
#pragma unroll
    for (int p = 0; p < 8; ++p)
      htp[ni][p] = (unsigned)f2bf(acc[ni][2 * p]) |
                   ((unsigned)f2bf(acc[ni][2 * p + 1]) << 16);
  // prefetch first GEMM2 B while writing sH
  auto loadB2 = [&](int sn, short8 (&bd)[4]) {
#pragma unroll
    for (int kh = 0; kh < 2; ++kh)
#pragma unroll
      for (int ni = 0; ni < 2; ++ni)
        bd[kh * 2 + ni] = *reinterpret_cast<const short8*>(
            fftps + (size_t)sn * 16384 + (kh * 2 + lh) * 4096 + (64 * w + 32 * ni + lr) * 8);
  };
  loadB2(0, b0);
#pragma unroll
  for (int q = 0; q < 4; ++q) {
    float4 stA = *reinterpret_cast<float4*>(&red[512 + (8 * q + 4 * lh) * 2]);
    float4 stB = *reinterpret_cast<float4*>(&red[512 + (8 * q + 4 * lh) * 2 + 4]);
    float mean[4] = {stA.x, stA.z, stB.x, stB.z};
    float rstd[4] = {stA.y, stA.w, stB.y, stB.w};
#pragma unroll
    for (int ni = 0; ni < 2; ++ni) {
      int col = 64 * w + 32 * ni + lr;
#pragma unroll
      for (int e = 0; e < 4; ++e) {
        int r = 4 * q + e;
        float z = (acc[ni][r] - mean[e]) * rstd[e];
        int rloc = 8 * q + 4 * lh + e;
        sH[(col >> 3) * 256 + rloc * 8 + (col & 7)] = (short)f2bf(z);
      }
    }
  }
#pragma unroll
  for (int ni = 0; ni < 2; ++ni)
#pragma unroll
    for (int e = 0; e < 16; ++e) acc[ni][e] = 0.f;
  barrier_lgkm();

  // ---- GEMM2: h_norm @ (fftp*g)^T, 16 K-steps, barrier-free ----
  auto mfstep2 = [&](int slotbase, short8 (&bc)[4]) {
    short8 af[2];
#pragma unroll
    for (int kh = 0; kh < 2; ++kh)
      af[kh] = *reinterpret_cast<const short8*>(
          &sH[(slotbase + kh * 2 + lh) * 256 + lr * 8]);
    __builtin_amdgcn_s_setprio(1);
#pragma unroll
    for (int kh = 0; kh < 2; ++kh)
#pragma unroll
      for (int ni = 0; ni < 2; ++ni)
        acc[ni] = mfma16(af[kh], bc[kh * 2 + ni], acc[ni]);
    __builtin_amdgcn_s_setprio(0);
  };
  for (int s = 0; s < 16; s += 2) {
    loadB2(s + 1, b1);
    mfstep2(s * 4, b0);
    if (s + 2 < 16) loadB2(s + 2, b0);
    mfstep2((s + 1) * 4, b1);
  }

  // ---- epilogue2: combine ----
  const float sg = 1.f / (1.f + expf(-fmix[0]));
  const float s2f = sg * sg, oms = 1.f - sg;
#pragma unroll
  for (int ni = 0; ni < 2; ++ni) {
    int col = 64 * w + 32 * ni + lr;
    float base = s2f * cvec[col] + sg * fftpb[col] + 0.5f * hm[bidx * 512 + col];
#pragma unroll
    for (int p = 0; p < 8; ++p) {
      unsigned pk = htp[ni][p];
      int r0 = 2 * p;
      int rloc = (r0 & 3) + 8 * (r0 >> 2) + 4 * lh;
      float o0 = oms * bf2f((unsigned short)(pk & 0xFFFF)) + s2f * acc[ni][r0] + base;
      float o1 = oms * bf2f((unsigned short)(pk >> 16)) + s2f * acc[ni][r0 + 1] + base;
      hs[(size_t)(m0 + rloc) * 512 + col] = o0;
      hs[(size_t)(m0 + rloc + 1) * 512 + col] = o1;
    }
  }
}

extern "C" void kernel_launch(void* const* d_in, const int* in_sizes, int n_in,
                              void* d_out, int out_size, void* d_ws, size_t ws_size,
                              hipStream_t stream) {
  (void)in_sizes; (void)n_in; (void)out_size; (void)ws_size;
  const float* x     = (const float*)d_in[0];
  const float* Wxw   = (const float*)d_in[1];
  const float* Wxb   = (const float*)d_in[2];
  const float* resa  = (const float*)d_in[4];
  const float* Bw    = (const float*)d_in[6];
  const float* Uw    = (const float*)d_in[7];
  const float* Ub    = (const float*)d_in[8];
  const float* fg    = (const float*)d_in[9];
  const float* fb    = (const float*)d_in[10];
  const float* fftpw = (const float*)d_in[11];
  const float* fftpb = (const float*)d_in[12];
  const float* fmix  = (const float*)d_in[13];
  const float* mixl  = (const float*)d_in[14];
  const float* keyw  = (const float*)d_in[15];
  const float* keyb  = (const float*)d_in[16];
  const float* rmw   = (const float*)d_in[19];
  const float* rmb   = (const float*)d_in[20];
  const float* rng   = (const float*)d_in[21];
  const float* rnb   = (const float*)d_in[22];
  const float* mkeys = (const float*)d_in[23];
  const float* mvals = (const float*)d_in[24];
  const float* hebH  = (const float*)d_in[25];

  float* outp = (float*)d_out;
  float* hs   = outp;                               // (B,T,512)
  float* rout = outp + (size_t)65536 * 512;         // (B,T,512)

  unsigned short* wsu = (unsigned short*)d_ws;
  unsigned short* wxp    = wsu;                     // 131072
  unsigned short* keyp   = wsu + 131072;            // 98304
  unsigned short* bwp    = wsu + 229376;            // 262144
  unsigned short* uwp    = wsu + 491520;            // 131072
  unsigned short* fftps  = wsu + 622592;            // 262144
  float* wsf     = (float*)d_ws;
  float* partial = wsf + 524288;                    // 512*128
  float* q_ws    = wsf + 589824;                    // 1024
  float* hm      = wsf + 590848;                    // 4096
  float* cvec    = wsf + 594944;                    // 512

  k_wconv<<<3456, 256, 0, stream>>>(Wxw, keyw, Bw, Uw, fftpw, fg,
                                    wxp, keyp, bwp, uwp, fftps);
  k_cvec <<<2,    256, 0, stream>>>(fb, fftpw, cvec);
  k_rseq <<<2048, 512, 0, stream>>>(x, wxp, Wxb, resa, rng, rnb, rout);
  k_kq   <<<512,  512, 0, stream>>>(rout, x, keyp, keyb, partial);
  k_qred <<<4,    256, 0, stream>>>(partial, q_ws);
  k_mem  <<<8,    256, 0, stream>>>(q_ws, mkeys, mvals, hebH, rmw, rmb, mixl, hm);
  k_fused<<<2048, 512, 0, stream>>>(rout, x, bwp, uwp, Ub, fftps, fftpb,
                                    fmix, cvec, hm, hs);
}

// Round 8
// 308.988 us; speedup vs baseline: 3.5118x; 1.0087x over previous
//
#include <hip/hip_runtime.h>
#include <cmath>

// CRSDCell bf16-MFMA pipeline, round 8: panel-staged barrier-free GEMMs.
//  - BM=32 blocks: whole A-panels fit LDS (x 16KB, r 32KB bf16) -> stage ONCE,
//    then GEMM K-loops are barrier-free with rolling reg B-prefetch.
//  - k_rk: fused r_seq + k/q-partials. r kept in LDS (no rseq re-read);
//    k-GEMM split-K across 2 wave-groups, f32 recombine in LDS.
//  - k_fused: stage sX+sR -> GEMM1 (24 free steps) -> LN -> sH overlays sR ->
//    GEMM2 (16 free steps) -> combine. 4 barriers total.
//  - Panel layout: P[(k>>3)*256 + row*8 + (k&7)] (k-slot, conflict-free b128).
// FFT folds exactly: irfft(rfft(h)*s) = s*h. h_prev=r_prev=0 kills Wh/A terms.

typedef __attribute__((ext_vector_type(8)))  short short8;
typedef __attribute__((ext_vector_type(16))) float f32x16;

__device__ __forceinline__ unsigned short f2bf(float f) {
  union { float f; unsigned u; } v; v.f = f;
  unsigned r = v.u + 0x7FFF + ((v.u >> 16) & 1);   // RTNE
  return (unsigned short)(r >> 16);
}
__device__ __forceinline__ float bf2f(unsigned short h) {
  union { unsigned u; float f; } v; v.u = ((unsigned)h) << 16; return v.f;
}
__device__ __forceinline__ f32x16 mfma16(short8 a, short8 b, f32x16 c) {
  return __builtin_amdgcn_mfma_f32_32x32x16_bf16(a, b, c, 0, 0, 0);
}
__device__ __forceinline__ void barrier_lgkm() {
  asm volatile("s_waitcnt lgkmcnt(0)" ::: "memory");
  __builtin_amdgcn_s_barrier();
  __builtin_amdgcn_sched_barrier(0);
}

// ---------------- weight convert + pack ----------------
// packed offset for (n,k) in [N][K]: (k>>5)*N*32 + ((k>>3)&3)*N*8 + n*8 + (k&7)
__global__ __launch_bounds__(256) void k_wconv(
    const float* __restrict__ wx, const float* __restrict__ key,
    const float* __restrict__ bw, const float* __restrict__ uw,
    const float* __restrict__ fftpw, const float* __restrict__ fg,
    unsigned short* __restrict__ wxp, unsigned short* __restrict__ keyp,
    unsigned short* __restrict__ bwp, unsigned short* __restrict__ uwp,
    unsigned short* __restrict__ fftps) {
  int i = blockIdx.x * 256 + threadIdx.x;
  if (i >= 884736) return;
  float v; int n, k, N; unsigned short* dst;
  if (i < 131072)      { int j = i;          N = 512; k = j & 255; n = j >> 8; v = wx[j];  dst = wxp; }
  else if (i < 229376) { int j = i - 131072; N = 128; k = j % 768; n = j / 768; v = key[j]; dst = keyp; }
  else if (i < 491520) { int j = i - 229376; N = 512; k = j & 511; n = j >> 9; v = bw[j];  dst = bwp; }
  else if (i < 622592) { int j = i - 491520; N = 512; k = j & 255; n = j >> 8; v = uw[j];  dst = uwp; }
  else                 { int j = i - 622592; N = 512; k = j & 511; n = j >> 9; v = fftpw[j] * fg[k]; dst = fftps; }
  dst[(k >> 5) * (N * 32) + ((k >> 3) & 3) * (N * 8) + n * 8 + (k & 7)] = f2bf(v);
}

// ---------------- K_RK: r_seq + k/q partials (BM=32) ----------------
__global__ __launch_bounds__(512, 4) void k_rk(
    const float* __restrict__ x, const unsigned short* __restrict__ wxp,
    const unsigned short* __restrict__ keyp,
    const float* __restrict__ wxb, const float* __restrict__ resa,
    const float* __restrict__ rng, const float* __restrict__ rnb,
    const float* __restrict__ keyb,
    float* __restrict__ rout, float* __restrict__ partial) {
  __shared__ short sX[8192];    // x panel  32x256 bf16 (16KB)
  __shared__ short sR[16384];   // r panel  32x512 bf16 (32KB); kp overlays later
  __shared__ float red[640];
  const int t = threadIdx.x, w = t >> 6, lane = t & 63, lr = lane & 31, lh = lane >> 5;
  const int m0 = blockIdx.x * 32;

  // ---- stage x panel ----
#pragma unroll
  for (int i = 0; i < 4; ++i) {
    int c = t + i * 512;                 // float4 idx; 64 per row
    int row = c >> 6, k0 = (c & 63) * 4;
    float4 v = *reinterpret_cast<const float4*>(x + (size_t)(m0 + row) * 256 + k0);
    uint2 p;
    p.x = (unsigned)f2bf(v.x) | ((unsigned)f2bf(v.y) << 16);
    p.y = (unsigned)f2bf(v.z) | ((unsigned)f2bf(v.w) << 16);
    *reinterpret_cast<uint2*>(&sX[(k0 >> 3) * 256 + row * 8 + (k0 & 7)]) = p;
  }
  barrier_lgkm();

  // ---- GEMM0: r_pre = x @ Wx^T, 8 barrier-free steps ----
  f32x16 acc[2];
#pragma unroll
  for (int ni = 0; ni < 2; ++ni)
#pragma unroll
    for (int e = 0; e < 16; ++e) acc[ni][e] = 0.f;
  short8 b0[4], b1[4];
  auto loadB0 = [&](int s, short8 (&bd)[4]) {
#pragma unroll
    for (int kh = 0; kh < 2; ++kh)
#pragma unroll
      for (int ni = 0; ni < 2; ++ni)
        bd[kh * 2 + ni] = *reinterpret_cast<const short8*>(
            wxp + (size_t)s * 16384 + (kh * 2 + lh) * 4096 + (64 * w + 32 * ni + lr) * 8);
  };
  auto mf0 = [&](int s, short8 (&bc)[4]) {
    short8 af[2];
#pragma unroll
    for (int kh = 0; kh < 2; ++kh)
      af[kh] = *reinterpret_cast<const short8*>(&sX[(s * 4 + kh * 2 + lh) * 256 + lr * 8]);
    __builtin_amdgcn_s_setprio(1);
#pragma unroll
    for (int kh = 0; kh < 2; ++kh)
#pragma unroll
      for (int ni = 0; ni < 2; ++ni)
        acc[ni] = mfma16(af[kh], bc[kh * 2 + ni], acc[ni]);
    __builtin_amdgcn_s_setprio(0);
  };
  loadB0(0, b0);
  for (int s = 0; s < 8; s += 2) {
    loadB0(s + 1, b1);
    mf0(s, b0);
    if (s + 2 < 8) loadB0(s + 2, b0);
    mf0(s + 1, b1);
  }

  // ---- epi0: z=(1-a)tanh(.+b), LN, write rout + sR ----
#pragma unroll
  for (int ni = 0; ni < 2; ++ni) {
    int col = 64 * w + 32 * ni + lr;
    float al = 1.f / (1.f + expf(-resa[col >> 7]));
    float oma = 1.f - al, bbv = wxb[col];
#pragma unroll
    for (int r = 0; r < 16; ++r)
      acc[ni][r] = oma * tanhf(acc[ni][r] + bbv);
  }
#pragma unroll
  for (int r = 0; r < 16; ++r) {
    float s1 = acc[0][r] + acc[1][r];
    float s2 = acc[0][r] * acc[0][r] + acc[1][r] * acc[1][r];
#pragma unroll
    for (int m = 1; m <= 16; m <<= 1) { s1 += __shfl_xor(s1, m); s2 += __shfl_xor(s2, m); }
    int rl = (r & 3) + 8 * (r >> 2) + 4 * lh;
    if (lr == r) { red[w * 32 + rl] = s1; red[256 + w * 32 + rl] = s2; }
  }
  __syncthreads();
  if (t < 32) {
    float s1 = 0.f, s2 = 0.f;
#pragma unroll
    for (int n = 0; n < 8; ++n) { s1 += red[n * 32 + t]; s2 += red[256 + n * 32 + t]; }
    float mean = s1 * (1.f / 512.f);
    float var = s2 * (1.f / 512.f) - mean * mean;
    float rstd = rsqrtf(var + 1e-5f);
    red[512 + t * 2] = mean;
    red[512 + t * 2 + 1] = rstd;
  }
  __syncthreads();
#pragma unroll
  for (int q = 0; q < 4; ++q) {
    float4 stA = *reinterpret_cast<float4*>(&red[512 + (8 * q + 4 * lh) * 2]);
    float4 stB = *reinterpret_cast<float4*>(&red[512 + (8 * q + 4 * lh) * 2 + 4]);
    float mean[4] = {stA.x, stA.z, stB.x, stB.z};
    float rstd[4] = {stA.y, stA.w, stB.y, stB.w};
#pragma unroll
    for (int ni = 0; ni < 2; ++ni) {
      int col = 64 * w + 32 * ni + lr;
      float g = rng[col], bbv = rnb[col];
#pragma unroll
      for (int e = 0; e < 4; ++e) {
        int r = 4 * q + e;
        int rloc = 8 * q + 4 * lh + e;
        float val = (acc[ni][r] - mean[e]) * rstd[e] * g + bbv;
        rout[(size_t)(m0 + rloc) * 512 + col] = val;
        sR[(col >> 3) * 256 + rloc * 8 + (col & 7)] = (short)f2bf(val);
      }
    }
  }
  barrier_lgkm();

  // ---- GEMM_k: k = [r,x] @ key^T, split-K over 2 wave-groups ----
  const int g = w >> 2, nw2 = w & 3;     // group, wave-in-group (32 cols each)
  f32x16 ak;
#pragma unroll
  for (int e = 0; e < 16; ++e) ak[e] = 0.f;
  short8 kb0[2], kb1[2];
  auto loadBk = [&](int gc, short8 (&bd)[2]) {
#pragma unroll
    for (int kh = 0; kh < 2; ++kh)
      bd[kh] = *reinterpret_cast<const short8*>(
          keyp + (size_t)gc * 4096 + (kh * 2 + lh) * 1024 + (32 * nw2 + lr) * 8);
  };
  auto mfk = [&](int gc, short8 (&bc)[2]) {
    const short* P = (gc < 16) ? sR : sX;
    int sb = (gc < 16) ? gc * 4 : (gc - 16) * 4;
    short8 af[2];
#pragma unroll
    for (int kh = 0; kh < 2; ++kh)
      af[kh] = *reinterpret_cast<const short8*>(&P[(sb + kh * 2 + lh) * 256 + lr * 8]);
    __builtin_amdgcn_s_setprio(1);
#pragma unroll
    for (int kh = 0; kh < 2; ++kh)
      ak = mfma16(af[kh], bc[kh], ak);
    __builtin_amdgcn_s_setprio(0);
  };
  const int gbase = g * 12;
  loadBk(gbase, kb0);
  for (int s = 0; s < 12; s += 2) {
    loadBk(gbase + s + 1, kb1);
    mfk(gbase + s, kb0);
    if (s + 2 < 12) loadBk(gbase + s + 2, kb0);
    mfk(gbase + s + 1, kb1);
  }
  __syncthreads();                        // all sR/sX reads done
  float* kp = reinterpret_cast<float*>(sR);  // kp[g][32 rows][128 cols]
#pragma unroll
  for (int r = 0; r < 16; ++r) {
    int rr = (r & 3) + 8 * (r >> 2) + 4 * lh;
    kp[g * 4096 + rr * 128 + nw2 * 32 + lr] = ak[r];
  }
  __syncthreads();
  // pass1: per-row sumsq -> scale
  {
    int rr = t >> 4, cg = t & 15;
    float s1 = 0.f;
#pragma unroll
    for (int j = 0; j < 8; ++j) {
      int c = cg * 8 + j;
      float v = kp[rr * 128 + c] + kp[4096 + rr * 128 + c] + keyb[c];
      s1 += v * v;
    }
#pragma unroll
    for (int m = 1; m <= 8; m <<= 1) s1 += __shfl_xor(s1, m);
    if (cg == 0) red[rr] = 1.f / fmaxf(sqrtf(s1), 1e-8f);
  }
  __syncthreads();
  // pass2: column partials of l2norm(k)
  if (t < 128) {
    float p = 0.f;
    float bb = keyb[t];
#pragma unroll 4
    for (int rr = 0; rr < 32; ++rr)
      p += (kp[rr * 128 + t] + kp[4096 + rr * 128 + t] + bb) * red[rr];
    partial[(size_t)blockIdx.x * 128 + t] = p;
  }
}

// ---------------- q reduce (2048 partial blocks, 256 per batch) -------------
__global__ __launch_bounds__(256) void k_qred(const float* __restrict__ partial,
                                              float* __restrict__ q_ws) {
  int gid = blockIdx.x * 256 + threadIdx.x;   // 0..1023
  int b = gid >> 7, c = gid & 127;
  float s = 0.f;
  for (int i = 0; i < 256; ++i) s += partial[(size_t)(b * 256 + i) * 128 + c];
  q_ws[gid] = s * (1.f / 8192.f);
}

// ---------------- cvec = fftn_b @ fftp_w^T (raw fftp) ----------------
__global__ __launch_bounds__(256) void k_cvec(const float* __restrict__ fb,
                                              const float* __restrict__ fftpw,
                                              float* __restrict__ cvec) {
  int o = blockIdx.x * 256 + threadIdx.x;     // 0..511
  const float* w = fftpw + (size_t)o * 512;
  float s = 0.f;
  for (int k = 0; k < 512; ++k) s += fb[k] * w[k];
  cvec[o] = s;
}

// ---------------- memory (episodic + hebbian) ----------------
__global__ __launch_bounds__(256) void k_mem(
    const float* __restrict__ q_ws, const float* __restrict__ mkeys,
    const float* __restrict__ mvals, const float* __restrict__ hebH,
    const float* __restrict__ rmw, const float* __restrict__ rmb,
    const float* __restrict__ mixl, float* __restrict__ hm) {
  const int b = blockIdx.x, t = threadIdx.x;
  __shared__ float qv[128];
  __shared__ float ssim[256];
  __shared__ float red[256];
  __shared__ float tval[8];
  __shared__ int tidx[8];
  __shared__ float wsm[8];
  __shared__ float vcs[128];

  if (t < 128) qv[t] = q_ws[b * 128 + t];
  __syncthreads();
  red[t] = (t < 128) ? qv[t] * qv[t] : 0.f;
  __syncthreads();
  for (int s = 128; s > 0; s >>= 1) {
    if (t < s) red[t] += red[t + s];
    __syncthreads();
  }
  float qsc = 1.f / fmaxf(sqrtf(red[0]), 1e-8f);
  {
    const float* mk = mkeys + ((size_t)b * 256 + t) * 128;
    float dot = 0.f, ms = 0.f;
    for (int k = 0; k < 128; ++k) { float mv = mk[k]; dot += qv[k] * mv; ms += mv * mv; }
    ssim[t] = dot * qsc / fmaxf(sqrtf(ms), 1e-8f);
  }
  __syncthreads();
  for (int it = 0; it < 8; ++it) {
    if (t < 64) {
      float bv = -1e30f; int bi = 0;
#pragma unroll
      for (int u = 0; u < 4; ++u) {
        int m = t * 4 + u;
        float v = ssim[m];
        if (v > bv) { bv = v; bi = m; }
      }
      for (int off = 32; off; off >>= 1) {
        float ov = __shfl_xor(bv, off, 64);
        int oi = __shfl_xor(bi, off, 64);
        if (ov > bv || (ov == bv && oi < bi)) { bv = ov; bi = oi; }
      }
      if (t == 0) { tval[it] = bv; tidx[it] = bi; ssim[bi] = -1e30f; }
    }
    __syncthreads();
  }
  if (t == 0) {
    float m0 = tval[0], sum = 0.f, e[8];
#pragma unroll
    for (int i = 0; i < 8; ++i) { e[i] = expf(tval[i] - m0); sum += e[i]; }
#pragma unroll
    for (int i = 0; i < 8; ++i) wsm[i] = e[i] / sum;
  }
  __syncthreads();
  float mix = 1.f / (1.f + expf(-mixl[0]));
  if (t < 128) {
    float vh = 0.f;
#pragma unroll
    for (int i = 0; i < 8; ++i) vh += wsm[i] * mvals[((size_t)b * 256 + tidx[i]) * 128 + t];
    float vhb = 0.f;
    const float* H = hebH + (size_t)b * 128 * 128;
    for (int k = 0; k < 128; ++k) vhb += qv[k] * H[k * 128 + t];
    vcs[t] = mix * vh + (1.f - mix) * vhb;
  }
  __syncthreads();
  for (int h = t; h < 512; h += 256) {
    float sum = rmb[h];
    const float* wr = rmw + (size_t)h * 128;
    for (int v = 0; v < 128; ++v) sum += vcs[v] * wr[v];
    hm[b * 512 + h] = sum;
  }
}

// ---------------- fused h_tilde -> LN -> fftp GEMM -> hs (BM=32) ------------
// LDS: sX 16K + sR 32K (sH overlays sR) + red 2.5K
__global__ __launch_bounds__(512, 4) void k_fused(
    const float* __restrict__ rseq, const float* __restrict__ x,
    const unsigned short* __restrict__ bwp, const unsigned short* __restrict__ uwp,
    const float* __restrict__ ub, const unsigned short* __restrict__ fftps,
    const float* __restrict__ fftpb, const float* __restrict__ fmix,
    const float* __restrict__ cvec, const float* __restrict__ hm,
    float* __restrict__ hs) {
  __shared__ short sX[8192];    // x panel 16KB
  __shared__ short sR[16384];   // r panel 32KB; h_norm overlays after GEMM1
  __shared__ float red[640];
  const int t = threadIdx.x, w = t >> 6, lane = t & 63, lr = lane & 31, lh = lane >> 5;
  const int m0 = blockIdx.x * 32;
  const int bidx = m0 >> 13;

  // ---- stage r panel (8 f4/thread) + x panel (4 f4/thread) ----
#pragma unroll
  for (int i = 0; i < 8; ++i) {
    int c = t + i * 512;                 // 128 float4 per row
    int row = c >> 7, k0 = (c & 127) * 4;
    float4 v = *reinterpret_cast<const float4*>(rseq + (size_t)(m0 + row) * 512 + k0);
    uint2 p;
    p.x = (unsigned)f2bf(v.x) | ((unsigned)f2bf(v.y) << 16);
    p.y = (unsigned)f2bf(v.z) | ((unsigned)f2bf(v.w) << 16);
    *reinterpret_cast<uint2*>(&sR[(k0 >> 3) * 256 + row * 8 + (k0 & 7)]) = p;
  }
#pragma unroll
  for (int i = 0; i < 4; ++i) {
    int c = t + i * 512;
    int row = c >> 6, k0 = (c & 63) * 4;
    float4 v = *reinterpret_cast<const float4*>(x + (size_t)(m0 + row) * 256 + k0);
    uint2 p;
    p.x = (unsigned)f2bf(v.x) | ((unsigned)f2bf(v.y) << 16);
    p.y = (unsigned)f2bf(v.z) | ((unsigned)f2bf(v.w) << 16);
    *reinterpret_cast<uint2*>(&sX[(k0 >> 3) * 256 + row * 8 + (k0 & 7)]) = p;
  }
  barrier_lgkm();

  // ---- GEMM1: h_pre = [r,x] @ [Bw,Uw]^T, 24 barrier-free steps ----
  f32x16 acc[2];
#pragma unroll
  for (int ni = 0; ni < 2; ++ni)
#pragma unroll
    for (int e = 0; e < 16; ++e) acc[ni][e] = 0.f;
  short8 b0[4], b1[4];
  auto loadB1 = [&](int s, short8 (&bd)[4]) {
    const unsigned short* wp = (s < 16) ? (bwp + (size_t)s * 16384)
                                        : (uwp + (size_t)(s - 16) * 16384);
#pragma unroll
    for (int kh = 0; kh < 2; ++kh)
#pragma unroll
      for (int ni = 0; ni < 2; ++ni)
        bd[kh * 2 + ni] = *reinterpret_cast<const short8*>(
            wp + (kh * 2 + lh) * 4096 + (64 * w + 32 * ni + lr) * 8);
  };
  auto mf1 = [&](int s, short8 (&bc)[4]) {
    const short* P = (s < 16) ? sR : sX;
    int sb = (s < 16) ? s * 4 : (s - 16) * 4;
    short8 af[2];
#pragma unroll
    for (int kh = 0; kh < 2; ++kh)
      af[kh] = *reinterpret_cast<const short8*>(&P[(sb + kh * 2 + lh) * 256 + lr * 8]);
    __builtin_amdgcn_s_setprio(1);
#pragma unroll
    for (int kh = 0; kh < 2; ++kh)
#pragma unroll
      for (int ni = 0; ni < 2; ++ni)
        acc[ni] = mfma16(af[kh], bc[kh * 2 + ni], acc[ni]);
    __builtin_amdgcn_s_setprio(0);
  };
  loadB1(0, b0);
  for (int s = 0; s < 24; s += 2) {
    loadB1(s + 1, b1);
    mf1(s, b0);
    if (s + 2 < 24) loadB1(s + 2, b0);
    mf1(s + 1, b1);
  }

  // ---- epi1: gelu, LN stats, pack h~, write sH (overlays sR) ----
#pragma unroll
  for (int ni = 0; ni < 2; ++ni) {
    int col = 64 * w + 32 * ni + lr;
    float ubc = ub[col];
#pragma unroll
    for (int r = 0; r < 16; ++r) {
      float pre = acc[ni][r] + ubc;
      acc[ni][r] = 0.5f * pre * (1.f + erff(pre * 0.70710678118654752f));
    }
  }
#pragma unroll
  for (int r = 0; r < 16; ++r) {
    float s1 = acc[0][r] + acc[1][r];
    float s2 = acc[0][r] * acc[0][r] + acc[1][r] * acc[1][r];
#pragma unroll
    for (int m = 1; m <= 16; m <<= 1) { s1 += __shfl_xor(s1, m); s2 += __shfl_xor(s2, m); }
    int rl = (r & 3) + 8 * (r >> 2) + 4 * lh;
    if (lr == r) { red[w * 32 + rl] = s1; red[256 + w * 32 + rl] = s2; }
  }
  __syncthreads();                         // also: all GEMM1 sR reads done
  if (t < 32) {
    float s1 = 0.f, s2 = 0.f;
#pragma unroll
    for (int n = 0; n < 8; ++n) { s1 += red[n * 32 + t]; s2 += red[256 + n * 32 + t]; }
    float mean = s1 * (1.f / 512.f);
    float var = s2 * (1.f / 512.f) - mean * mean;
    float rstd = rsqrtf(var + 1e-5f);
    red[512 + t * 2] = mean;
    red[512 + t * 2 + 1] = rstd;
  }
  __syncthreads();
  unsigned htp[2][8];
#pragma unroll
  for (int ni = 0; ni < 2; ++ni)
#pragma unroll
    for (int p = 0; p < 8; ++p)
      htp[ni][p] = (unsigned)f2bf(acc[ni][2 * p]) |
                   ((unsigned)f2bf(acc[ni][2 * p + 1]) << 16);
  auto loadB2 = [&](int s, short8 (&bd)[4]) {
#pragma unroll
    for (int kh = 0; kh < 2; ++kh)
#pragma unroll
      for (int ni = 0; ni < 2; ++ni)
        bd[kh * 2 + ni] = *reinterpret_cast<const short8*>(
            fftps + (size_t)s * 16384 + (kh * 2 + lh) * 4096 + (64 * w + 32 * ni + lr) * 8);
  };
  loadB2(0, b0);                           // prefetch under sH writes
#pragma unroll
  for (int q = 0; q < 4; ++q) {
    float4 stA = *reinterpret_cast<float4*>(&red[512 + (8 * q + 4 * lh) * 2]);
    float4 stB = *reinterpret_cast<float4*>(&red[512 + (8 * q + 4 * lh) * 2 + 4]);
    float mean[4] = {stA.x, stA.z, stB.x, stB.z};
    float rstd[4] = {stA.y, stA.w, stB.y, stB.w};
#pragma unroll
    for (int ni = 0; ni < 2; ++ni) {
      int col = 64 * w + 32 * ni + lr;
#pragma unroll
      for (int e = 0; e < 4; ++e) {
        int r = 4 * q + e;
        float z = (acc[ni][r] - mean[e]) * rstd[e];
        int rloc = 8 * q + 4 * lh + e;
        sR[(col >> 3) * 256 + rloc * 8 + (col & 7)] = (short)f2bf(z);
      }
    }
  }
#pragma unroll
  for (int ni = 0; ni < 2; ++ni)
#pragma unroll
    for (int e = 0; e < 16; ++e) acc[ni][e] = 0.f;
  barrier_lgkm();

  // ---- GEMM2: h_norm @ (fftp*g)^T, 16 barrier-free steps ----
  auto mf2 = [&](int s, short8 (&bc)[4]) {
    short8 af[2];
#pragma unroll
    for (int kh = 0; kh < 2; ++kh)
      af[kh] = *reinterpret_cast<const short8*>(&sR[(s * 4 + kh * 2 + lh) * 256 + lr * 8]);
    __builtin_amdgcn_s_setprio(1);
#pragma unroll
    for (int kh = 0; kh < 2; ++kh)
#pragma unroll
      for (int ni = 0; ni < 2; ++ni)
        acc[ni] = mfma16(af[kh], bc[kh * 2 + ni], acc[ni]);
    __builtin_amdgcn_s_setprio(0);
  };
  for (int s = 0; s < 16; s += 2) {
    loadB2(s + 1, b1);
    mf2(s, b0);
    if (s + 2 < 16) loadB2(s + 2, b0);
    mf2(s + 1, b1);
  }

  // ---- epi2: combine ----
  const float sg = 1.f / (1.f + expf(-fmix[0]));
  const float s2f = sg * sg, oms = 1.f - sg;
#pragma unroll
  for (int ni = 0; ni < 2; ++ni) {
    int col = 64 * w + 32 * ni + lr;
    float base = s2f * cvec[col] + sg * fftpb[col] + 0.5f * hm[bidx * 512 + col];
#pragma unroll
    for (int p = 0; p < 8; ++p) {
      unsigned pk = htp[ni][p];
      int r0 = 2 * p;
      int rloc = (r0 & 3) + 8 * (r0 >> 2) + 4 * lh;
      float o0 = oms * bf2f((unsigned short)(pk & 0xFFFF)) + s2f * acc[ni][r0] + base;
      float o1 = oms * bf2f((unsigned short)(pk >> 16)) + s2f * acc[ni][r0 + 1] + base;
      hs[(size_t)(m0 + rloc) * 512 + col] = o0;
      hs[(size_t)(m0 + rloc + 1) * 512 + col] = o1;
    }
  }
}

extern "C" void kernel_launch(void* const* d_in, const int* in_sizes, int n_in,
                              void* d_out, int out_size, void* d_ws, size_t ws_size,
                              hipStream_t stream) {
  (void)in_sizes; (void)n_in; (void)out_size; (void)ws_size;
  const float* x     = (const float*)d_in[0];
  const float* Wxw   = (const float*)d_in[1];
  const float* Wxb   = (const float*)d_in[2];
  const float* resa  = (const float*)d_in[4];
  const float* Bw    = (const float*)d_in[6];
  const float* Uw    = (const float*)d_in[7];
  const float* Ub    = (const float*)d_in[8];
  const float* fg    = (const float*)d_in[9];
  const float* fb    = (const float*)d_in[10];
  const float* fftpw = (const float*)d_in[11];
  const float* fftpb = (const float*)d_in[12];
  const float* fmix  = (const float*)d_in[13];
  const float* mixl  = (const float*)d_in[14];
  const float* keyw  = (const float*)d_in[15];
  const float* keyb  = (const float*)d_in[16];
  const float* rmw   = (const float*)d_in[19];
  const float* rmb   = (const float*)d_in[20];
  const float* rng   = (const float*)d_in[21];
  const float* rnb   = (const float*)d_in[22];
  const float* mkeys = (const float*)d_in[23];
  const float* mvals = (const float*)d_in[24];
  const float* hebH  = (const float*)d_in[25];

  float* outp = (float*)d_out;
  float* hs   = outp;                               // (B,T,512)
  float* rout = outp + (size_t)65536 * 512;         // (B,T,512)

  unsigned short* wsu = (unsigned short*)d_ws;
  unsigned short* wxp    = wsu;                     // 131072
  unsigned short* keyp   = wsu + 131072;            // 98304
  unsigned short* bwp    = wsu + 229376;            // 262144
  unsigned short* uwp    = wsu + 491520;            // 131072
  unsigned short* fftps  = wsu + 622592;            // 262144
  float* wsf     = (float*)d_ws;
  float* partial = wsf + 524288;                    // 2048*128 = 262144
  float* q_ws    = wsf + 786432;                    // 1024
  float* hm      = wsf + 787456;                    // 4096
  float* cvec    = wsf + 791552;                    // 512

  k_wconv<<<3456, 256, 0, stream>>>(Wxw, keyw, Bw, Uw, fftpw, fg,
                                    wxp, keyp, bwp, uwp, fftps);
  k_cvec <<<2,    256, 0, stream>>>(fb, fftpw, cvec);
  k_rk   <<<2048, 512, 0, stream>>>(x, wxp, keyp, Wxb, resa, rng, rnb, keyb,
                                    rout, partial);
  k_qred <<<4,    256, 0, stream>>>(partial, q_ws);
  k_mem  <<<8,    256, 0, stream>>>(q_ws, mkeys, mvals, hebH, rmw, rmb, mixl, hm);
  k_fused<<<2048, 512, 0, stream>>>(rout, x, bwp, uwp, Ub, fftps, fftpb,
                                    fmix, cvec, hm, hs);
}